// Round 1
// baseline (420.096 us; speedup 1.0000x reference)
//
#include <hip/hip_runtime.h>

#define FDIM 256
#define EDIM 64
#define LEAKY 0.2f

// GEMM tiling
#define TM 64
#define TN 128
#define BK 32

__device__ __forceinline__ void atomic_max_float(float* addr, float val){
    if (val >= 0.f) atomicMax((int*)addr, __float_as_int(val));
    else            atomicMin((unsigned int*)addr, (unsigned int)__float_as_int(val));
}

__global__ void k_init(float* __restrict__ m, float* __restrict__ denom,
                       int* __restrict__ counts, int N){
    int i = blockIdx.x*256 + threadIdx.x;
    if (i < N){ m[i] = -3.402823466e38f; denom[i] = 0.f; counts[i] = 0; }
}

// z = h @ W^T : (M x 256) x (256 x 256)^T, fp32
__global__ __launch_bounds__(256) void k_gemm(const float* __restrict__ h,
                                              const float* __restrict__ W,
                                              float* __restrict__ z, int M){
    __shared__ float As[BK][TM+4];
    __shared__ float Bs[BK][TN+4];
    int tid = threadIdx.x;
    int tx = tid & 15;   // col group: 8 cols
    int ty = tid >> 4;   // row group: 4 rows
    int m0 = blockIdx.x * TM;
    int n0 = blockIdx.y * TN;
    float acc[4][8];
    #pragma unroll
    for (int r=0;r<4;r++)
        #pragma unroll
        for (int c=0;c<8;c++) acc[r][c]=0.f;

    for (int kc = 0; kc < FDIM; kc += BK){
        // A tile: TM rows x BK k, stored transposed As[k][row]
        #pragma unroll
        for (int u = tid; u < TM*(BK/4); u += 256){
            int r = u >> 3, c4 = u & 7;
            int gr = m0 + r;
            float4 v = make_float4(0.f,0.f,0.f,0.f);
            if (gr < M) v = *(const float4*)&h[gr*FDIM + kc + c4*4];
            As[c4*4+0][r]=v.x; As[c4*4+1][r]=v.y; As[c4*4+2][r]=v.z; As[c4*4+3][r]=v.w;
        }
        // B tile: TN rows (output cols j) x BK k, Bs[k][j]
        #pragma unroll
        for (int u = tid; u < TN*(BK/4); u += 256){
            int r = u >> 3, c4 = u & 7;
            int gr = n0 + r;   // always < 256
            float4 v = *(const float4*)&W[gr*FDIM + kc + c4*4];
            Bs[c4*4+0][r]=v.x; Bs[c4*4+1][r]=v.y; Bs[c4*4+2][r]=v.z; Bs[c4*4+3][r]=v.w;
        }
        __syncthreads();
        #pragma unroll
        for (int k=0;k<BK;k++){
            float4 a  = *(const float4*)&As[k][ty*4];
            float4 b0 = *(const float4*)&Bs[k][tx*8];
            float4 b1 = *(const float4*)&Bs[k][tx*8+4];
            float ar[4] = {a.x,a.y,a.z,a.w};
            float bc[8] = {b0.x,b0.y,b0.z,b0.w,b1.x,b1.y,b1.z,b1.w};
            #pragma unroll
            for (int r=0;r<4;r++)
                #pragma unroll
                for (int c=0;c<8;c++)
                    acc[r][c] += ar[r]*bc[c];
        }
        __syncthreads();
    }
    #pragma unroll
    for (int r=0;r<4;r++){
        int gr = m0 + ty*4 + r;
        if (gr < M){
            float4 s0 = make_float4(acc[r][0],acc[r][1],acc[r][2],acc[r][3]);
            float4 s1 = make_float4(acc[r][4],acc[r][5],acc[r][6],acc[r][7]);
            *(float4*)&z[gr*FDIM + n0 + tx*8]     = s0;
            *(float4*)&z[gr*FDIM + n0 + tx*8 + 4] = s1;
        }
    }
}

// per-node s_src, s_dst (one 64-lane wave per node)
__global__ void k_sdots(const float* __restrict__ z, const float* __restrict__ A,
                        float* __restrict__ s_src, float* __restrict__ s_dst, int N){
    int gt = blockIdx.x*256 + threadIdx.x;
    int w = gt >> 6, lane = gt & 63;
    if (w >= N) return;
    float4 zv = *(const float4*)&z[w*FDIM + lane*4];
    float4 as = *(const float4*)&A[lane*4];
    float4 ad = *(const float4*)&A[FDIM + lane*4];
    float vs = zv.x*as.x + zv.y*as.y + zv.z*as.z + zv.w*as.w;
    float vd = zv.x*ad.x + zv.y*ad.y + zv.z*ad.z + zv.w*ad.w;
    #pragma unroll
    for (int o = 32; o > 0; o >>= 1){
        vs += __shfl_xor(vs, o);
        vd += __shfl_xor(vd, o);
    }
    if (lane == 0){ s_src[w] = vs; s_dst[w] = vd; }
}

// per-edge logits + leaky relu + segment-max + degree histogram (16 lanes/edge)
__global__ void k_edge(const float* __restrict__ ef, const float* __restrict__ A,
                       const float* __restrict__ s_src, const float* __restrict__ s_dst,
                       const int* __restrict__ src, const int* __restrict__ dst,
                       float* __restrict__ elog, float* __restrict__ m,
                       int* __restrict__ counts, int E){
    int gt = blockIdx.x*256 + threadIdx.x;
    int e = gt >> 4, l4 = gt & 15;
    if (e >= E) return;
    float4 f  = *(const float4*)&ef[e*EDIM + l4*4];
    float4 ae = *(const float4*)&A[2*FDIM + l4*4];
    float v = f.x*ae.x + f.y*ae.y + f.z*ae.z + f.w*ae.w;
    v += __shfl_xor(v, 8); v += __shfl_xor(v, 4);
    v += __shfl_xor(v, 2); v += __shfl_xor(v, 1);
    if (l4 == 0){
        int d = dst[e];
        float lg = v + s_src[src[e]] + s_dst[d];
        lg = lg > 0.f ? lg : LEAKY*lg;
        elog[e] = lg;
        atomic_max_float(&m[d], lg);
        atomicAdd(&counts[d], 1);
    }
}

// scan phase 1: per-1024-chunk sums
__global__ void k_chunk_sums(const int* __restrict__ counts, int* __restrict__ bsums, int N){
    __shared__ int sh[256];
    int base = blockIdx.x*1024;
    int s = 0;
    for (int i = threadIdx.x; i < 1024; i += 256){
        int idx = base + i;
        s += (idx < N) ? counts[idx] : 0;
    }
    sh[threadIdx.x] = s; __syncthreads();
    for (int o = 128; o > 0; o >>= 1){
        if (threadIdx.x < o) sh[threadIdx.x] += sh[threadIdx.x + o];
        __syncthreads();
    }
    if (threadIdx.x == 0) bsums[blockIdx.x] = sh[0];
}

// scan phase 2: exclusive scan of chunk sums (nb <= 1024), single block
__global__ void k_scan_small(int* __restrict__ b, int nb){
    __shared__ int sh[1024];
    int tid = threadIdx.x;
    int v = (tid < nb) ? b[tid] : 0;
    sh[tid] = v; __syncthreads();
    int acc = v;
    for (int o = 1; o < 1024; o <<= 1){
        int t = (tid >= o) ? sh[tid - o] : 0;
        __syncthreads();
        acc += t; sh[tid] = acc;
        __syncthreads();
    }
    if (tid < nb) b[tid] = acc - v;
}

// scan phase 3: per-chunk exclusive scan -> offsets (in place over counts) + cursor copy
__global__ void k_scan_chunks(int* __restrict__ counts, int* __restrict__ cursor,
                              const int* __restrict__ bsums, int N, int E){
    __shared__ int sh[256];
    int tid = threadIdx.x;
    int base = blockIdx.x*1024 + tid*4;
    int v[4]; int s = 0;
    #pragma unroll
    for (int l = 0; l < 4; l++){
        int idx = base + l;
        v[l] = (idx < N) ? counts[idx] : 0;
        s += v[l];
    }
    sh[tid] = s; __syncthreads();
    int acc = s;
    for (int o = 1; o < 256; o <<= 1){
        int t = (tid >= o) ? sh[tid - o] : 0;
        __syncthreads();
        acc += t; sh[tid] = acc;
        __syncthreads();
    }
    int excl = acc - s + bsums[blockIdx.x];
    #pragma unroll
    for (int l = 0; l < 4; l++){
        int idx = base + l;
        if (idx < N){ counts[idx] = excl; cursor[idx] = excl; }
        excl += v[l];
    }
    if (blockIdx.x == 0 && tid == 0) counts[N] = E;
}

// exp + denom accumulation + counting-sort scatter
__global__ void k_scatter(const float* __restrict__ elog, const float* __restrict__ m,
                          const int* __restrict__ src, const int* __restrict__ dst,
                          float* __restrict__ denom, int* __restrict__ cursor,
                          int* __restrict__ srcs_s, float* __restrict__ wsort, int E){
    int e = blockIdx.x*256 + threadIdx.x;
    if (e >= E) return;
    int d = dst[e];
    float ex = __expf(elog[e] - m[d]);
    atomicAdd(&denom[d], ex);
    int p = atomicAdd(&cursor[d], 1);
    srcs_s[p] = src[e];
    wsort[p]  = ex;
}

// final: one block per dst node, accumulate alpha * z[src]
__global__ __launch_bounds__(256) void k_out(const float* __restrict__ z,
                                             const int* __restrict__ offsets,
                                             const int* __restrict__ srcs_s,
                                             const float* __restrict__ wsort,
                                             const float* __restrict__ denom,
                                             float* __restrict__ out, int N){
    int n = blockIdx.x;
    int t = threadIdx.x;
    int i0 = offsets[n], i1 = offsets[n+1];
    float acc0 = 0.f, acc1 = 0.f;
    int i = i0;
    for (; i + 1 < i1; i += 2){
        float w0 = wsort[i],   w1 = wsort[i+1];
        int   s0 = srcs_s[i],  s1 = srcs_s[i+1];
        acc0 += w0 * z[s0*FDIM + t];
        acc1 += w1 * z[s1*FDIM + t];
    }
    if (i < i1){
        acc0 += wsort[i] * z[srcs_s[i]*FDIM + t];
    }
    float res = (i1 > i0) ? (acc0 + acc1) / denom[n] : 0.f;
    out[n*FDIM + t] = res;
}

extern "C" void kernel_launch(void* const* d_in, const int* in_sizes, int n_in,
                              void* d_out, int out_size, void* d_ws, size_t ws_size,
                              hipStream_t stream){
    const float* h  = (const float*)d_in[0];
    const float* ef = (const float*)d_in[1];
    const float* W  = (const float*)d_in[2];
    const float* A  = (const float*)d_in[3];
    const int*  src = (const int*)d_in[4];
    const int*  dst = (const int*)d_in[5];
    float* out = (float*)d_out;
    int N = in_sizes[0] / FDIM;
    int E = in_sizes[4];

    char* ws = (char*)d_ws;
    size_t off = 0;
    auto alloc = [&](size_t nbytes)->char*{
        char* p = ws + off;
        off = (off + nbytes + 255) & ~(size_t)255;
        return p;
    };
    float* z      = (float*)alloc((size_t)N*FDIM*4);
    float* s_src  = (float*)alloc((size_t)N*4);
    float* s_dst  = (float*)alloc((size_t)N*4);
    float* mbuf   = (float*)alloc((size_t)N*4);
    float* denom  = (float*)alloc((size_t)N*4);
    float* elog   = (float*)alloc((size_t)E*4);
    int*   counts = (int*)alloc((size_t)(N+1)*4);
    int*   cursor = (int*)alloc((size_t)N*4);
    int*   srcs_s = (int*)alloc((size_t)E*4);
    float* wsort  = (float*)alloc((size_t)E*4);
    int*   bsums  = (int*)alloc(1024*4);

    int nb = (N + 1023)/1024;

    hipLaunchKernelGGL(k_init, dim3((N+255)/256), dim3(256), 0, stream,
                       mbuf, denom, counts, N);
    hipLaunchKernelGGL(k_gemm, dim3((N+TM-1)/TM, FDIM/TN), dim3(256), 0, stream,
                       h, W, z, N);
    hipLaunchKernelGGL(k_sdots, dim3((N+3)/4), dim3(256), 0, stream,
                       z, A, s_src, s_dst, N);
    hipLaunchKernelGGL(k_edge, dim3((E+15)/16), dim3(256), 0, stream,
                       ef, A, s_src, s_dst, src, dst, elog, mbuf, counts, E);
    hipLaunchKernelGGL(k_chunk_sums, dim3(nb), dim3(256), 0, stream,
                       counts, bsums, N);
    hipLaunchKernelGGL(k_scan_small, dim3(1), dim3(1024), 0, stream,
                       bsums, nb);
    hipLaunchKernelGGL(k_scan_chunks, dim3(nb), dim3(256), 0, stream,
                       counts, cursor, bsums, N, E);
    hipLaunchKernelGGL(k_scatter, dim3((E+255)/256), dim3(256), 0, stream,
                       elog, mbuf, src, dst, denom, cursor, srcs_s, wsort, E);
    hipLaunchKernelGGL(k_out, dim3(N), dim3(256), 0, stream,
                       z, counts, srcs_s, wsort, denom, out, N);
}

// Round 3
// 354.387 us; speedup vs baseline: 1.1854x; 1.1854x over previous
//
#include <hip/hip_runtime.h>
#include <hip/hip_bf16.h>

#define FDIM 256
#define EDIM 64
#define LEAKY 0.2f

// MFMA GEMM tiling
#define BM 128
#define BN 128
#define BK 32

typedef __attribute__((ext_vector_type(8))) short bfrag;   // 8 bf16 = 4 VGPR
typedef __attribute__((ext_vector_type(4))) float f4acc;   // 4 f32 accum

// fp32 -> bf16 bits, round-to-nearest-even
__device__ __forceinline__ unsigned f2bf(float x){
    unsigned u = __float_as_uint(x);
    return (u + 0x7FFFu + ((u >> 16) & 1u)) >> 16;
}
// exact float value of a bf16 bit pattern
__device__ __forceinline__ float bf2f(unsigned b){
    return __uint_as_float(b << 16);
}
// pack two floats -> {hi-pair bits, and their exact float values}
__device__ __forceinline__ unsigned pack_hi(float x, float y, float& hx, float& hy){
    unsigned bx = f2bf(x), by = f2bf(y);
    hx = bf2f(bx); hy = bf2f(by);
    return bx | (by << 16);
}
__device__ __forceinline__ unsigned pack_lo(float rx, float ry){
    return f2bf(rx) | (f2bf(ry) << 16);
}

__device__ __forceinline__ void atomic_max_float(float* addr, float val){
    if (val >= 0.f) atomicMax((int*)addr, __float_as_int(val));
    else            atomicMin((unsigned int*)addr, (unsigned int)__float_as_int(val));
}

__global__ void k_init(float* __restrict__ m, float* __restrict__ denom,
                       int* __restrict__ counts, int N){
    int i = blockIdx.x*256 + threadIdx.x;
    if (i < N){ m[i] = -3.402823466e38f; denom[i] = 0.f; counts[i] = 0; }
}

// z = h @ W^T via split-bf16 MFMA: x = hi + lo (bf16 each),
// acc += Ah*Bh + Al*Bh + Ah*Bl  (lo*lo dropped, ~2^-16 relative)
__global__ __launch_bounds__(256, 2) void k_gemm(const float* __restrict__ h,
                                                 const float* __restrict__ W,
                                                 float* __restrict__ z, int M){
    // LDS: per row 128B = 4 slots hi (k0..31) + 4 slots lo, slot swizzled ^ (row&7)
    __shared__ uint4 smA[BM*8];
    __shared__ uint4 smB[BN*8];

    int tid = threadIdx.x;
    int m0 = blockIdx.x * BM;
    int n0 = blockIdx.y * BN;

    int wid  = tid >> 6;
    int lane = tid & 63;
    int wm = (wid >> 1) * 64;   // wave m-offset in tile
    int wn = (wid & 1) * 64;    // wave n-offset in tile
    int l15 = lane & 15;
    int l4  = lane >> 4;

    f4acc acc[4][4];
    #pragma unroll
    for (int i = 0; i < 4; ++i)
        #pragma unroll
        for (int j = 0; j < 4; ++j)
            acc[i][j] = (f4acc)(0.f);

    for (int kc = 0; kc < FDIM; kc += BK){
        // ---- stage: 1024 (row,k8) pairs, 4 per thread; convert fp32 -> hi/lo bf16
        #pragma unroll
        for (int q = 0; q < 4; ++q){
            int p = tid + q*256;          // 0..511 = A, 512..1023 = B
            int isB = p >= 512;
            int pp = p & 511;
            int row = pp >> 2, k8 = pp & 3;
            float4 v0, v1;
            if (isB){
                const float* g = &W[(n0 + row)*FDIM + kc + k8*8];
                v0 = *(const float4*)g; v1 = *(const float4*)(g + 4);
            } else {
                int gr = m0 + row;
                if (gr < M){
                    const float* g = &h[gr*FDIM + kc + k8*8];
                    v0 = *(const float4*)g; v1 = *(const float4*)(g + 4);
                } else {
                    v0 = make_float4(0.f,0.f,0.f,0.f); v1 = v0;
                }
            }
            uint4 hi, lo;
            float hx, hy;
            hi.x = pack_hi(v0.x, v0.y, hx, hy);
            lo.x = pack_lo(v0.x - hx, v0.y - hy);
            hi.y = pack_hi(v0.z, v0.w, hx, hy);
            lo.y = pack_lo(v0.z - hx, v0.w - hy);
            hi.z = pack_hi(v1.x, v1.y, hx, hy);
            lo.z = pack_lo(v1.x - hx, v1.y - hy);
            hi.w = pack_hi(v1.z, v1.w, hx, hy);
            lo.w = pack_lo(v1.z - hx, v1.w - hy);

            uint4* base = isB ? smB : smA;
            int sh = k8 ^ (row & 7);
            base[row*8 + sh]       = hi;
            base[row*8 + (sh ^ 4)] = lo;
        }
        __syncthreads();

        // ---- compute: per wave 4x4 fragments of 16x16, 3 MFMA each
        bfrag ah[4], al[4];
        #pragma unroll
        for (int mf = 0; mf < 4; ++mf){
            int row = wm + mf*16 + l15;
            int sh = l4 ^ (row & 7);
            ah[mf] = *(const bfrag*)&smA[row*8 + sh];
            al[mf] = *(const bfrag*)&smA[row*8 + (sh ^ 4)];
        }
        #pragma unroll
        for (int nf = 0; nf < 4; ++nf){
            int row = wn + nf*16 + l15;
            int sh = l4 ^ (row & 7);
            bfrag bh = *(const bfrag*)&smB[row*8 + sh];
            bfrag bl = *(const bfrag*)&smB[row*8 + (sh ^ 4)];
            #pragma unroll
            for (int mf = 0; mf < 4; ++mf){
                acc[mf][nf] = __builtin_amdgcn_mfma_f32_16x16x32_bf16(ah[mf], bh, acc[mf][nf], 0, 0, 0);
                acc[mf][nf] = __builtin_amdgcn_mfma_f32_16x16x32_bf16(al[mf], bh, acc[mf][nf], 0, 0, 0);
                acc[mf][nf] = __builtin_amdgcn_mfma_f32_16x16x32_bf16(ah[mf], bl, acc[mf][nf], 0, 0, 0);
            }
        }
        __syncthreads();
    }

    // ---- epilogue: C/D layout col=lane&15, row=(lane>>4)*4+reg
    #pragma unroll
    for (int mf = 0; mf < 4; ++mf){
        #pragma unroll
        for (int nf = 0; nf < 4; ++nf){
            int gcol = n0 + wn + nf*16 + l15;
            #pragma unroll
            for (int r = 0; r < 4; ++r){
                int grow = m0 + wm + mf*16 + l4*4 + r;
                if (grow < M) z[(size_t)grow*FDIM + gcol] = acc[mf][nf][r];
            }
        }
    }
}

// per-node s_src, s_dst (one 64-lane wave per node)
__global__ void k_sdots(const float* __restrict__ z, const float* __restrict__ A,
                        float* __restrict__ s_src, float* __restrict__ s_dst, int N){
    int gt = blockIdx.x*256 + threadIdx.x;
    int w = gt >> 6, lane = gt & 63;
    if (w >= N) return;
    float4 zv = *(const float4*)&z[w*FDIM + lane*4];
    float4 as = *(const float4*)&A[lane*4];
    float4 ad = *(const float4*)&A[FDIM + lane*4];
    float vs = zv.x*as.x + zv.y*as.y + zv.z*as.z + zv.w*as.w;
    float vd = zv.x*ad.x + zv.y*ad.y + zv.z*ad.z + zv.w*ad.w;
    #pragma unroll
    for (int o = 32; o > 0; o >>= 1){
        vs += __shfl_xor(vs, o);
        vd += __shfl_xor(vd, o);
    }
    if (lane == 0){ s_src[w] = vs; s_dst[w] = vd; }
}

// per-edge logits + leaky relu + segment-max + degree histogram (16 lanes/edge)
__global__ void k_edge(const float* __restrict__ ef, const float* __restrict__ A,
                       const float* __restrict__ s_src, const float* __restrict__ s_dst,
                       const int* __restrict__ src, const int* __restrict__ dst,
                       float* __restrict__ elog, float* __restrict__ m,
                       int* __restrict__ counts, int E){
    int gt = blockIdx.x*256 + threadIdx.x;
    int e = gt >> 4, l4 = gt & 15;
    if (e >= E) return;
    float4 f  = *(const float4*)&ef[e*EDIM + l4*4];
    float4 ae = *(const float4*)&A[2*FDIM + l4*4];
    float v = f.x*ae.x + f.y*ae.y + f.z*ae.z + f.w*ae.w;
    v += __shfl_xor(v, 8); v += __shfl_xor(v, 4);
    v += __shfl_xor(v, 2); v += __shfl_xor(v, 1);
    if (l4 == 0){
        int d = dst[e];
        float lg = v + s_src[src[e]] + s_dst[d];
        lg = lg > 0.f ? lg : LEAKY*lg;
        elog[e] = lg;
        atomic_max_float(&m[d], lg);
        atomicAdd(&counts[d], 1);
    }
}

// scan phase 1: per-1024-chunk sums
__global__ void k_chunk_sums(const int* __restrict__ counts, int* __restrict__ bsums, int N){
    __shared__ int sh[256];
    int base = blockIdx.x*1024;
    int s = 0;
    for (int i = threadIdx.x; i < 1024; i += 256){
        int idx = base + i;
        s += (idx < N) ? counts[idx] : 0;
    }
    sh[threadIdx.x] = s; __syncthreads();
    for (int o = 128; o > 0; o >>= 1){
        if (threadIdx.x < o) sh[threadIdx.x] += sh[threadIdx.x + o];
        __syncthreads();
    }
    if (threadIdx.x == 0) bsums[blockIdx.x] = sh[0];
}

// scan phase 2: exclusive scan of chunk sums (nb <= 1024), single block
__global__ void k_scan_small(int* __restrict__ b, int nb){
    __shared__ int sh[1024];
    int tid = threadIdx.x;
    int v = (tid < nb) ? b[tid] : 0;
    sh[tid] = v; __syncthreads();
    int acc = v;
    for (int o = 1; o < 1024; o <<= 1){
        int t = (tid >= o) ? sh[tid - o] : 0;
        __syncthreads();
        acc += t; sh[tid] = acc;
        __syncthreads();
    }
    if (tid < nb) b[tid] = acc - v;
}

// scan phase 3: per-chunk exclusive scan -> offsets (in place) + cursor copy
__global__ void k_scan_chunks(int* __restrict__ counts, int* __restrict__ cursor,
                              const int* __restrict__ bsums, int N, int E){
    __shared__ int sh[256];
    int tid = threadIdx.x;
    int base = blockIdx.x*1024 + tid*4;
    int v[4]; int s = 0;
    #pragma unroll
    for (int l = 0; l < 4; l++){
        int idx = base + l;
        v[l] = (idx < N) ? counts[idx] : 0;
        s += v[l];
    }
    sh[tid] = s; __syncthreads();
    int acc = s;
    for (int o = 1; o < 256; o <<= 1){
        int t = (tid >= o) ? sh[tid - o] : 0;
        __syncthreads();
        acc += t; sh[tid] = acc;
        __syncthreads();
    }
    int excl = acc - s + bsums[blockIdx.x];
    #pragma unroll
    for (int l = 0; l < 4; l++){
        int idx = base + l;
        if (idx < N){ counts[idx] = excl; cursor[idx] = excl; }
        excl += v[l];
    }
    if (blockIdx.x == 0 && tid == 0) counts[N] = E;
}

// exp + denom accumulation + counting-sort scatter
__global__ void k_scatter(const float* __restrict__ elog, const float* __restrict__ m,
                          const int* __restrict__ src, const int* __restrict__ dst,
                          float* __restrict__ denom, int* __restrict__ cursor,
                          int* __restrict__ srcs_s, float* __restrict__ wsort, int E){
    int e = blockIdx.x*256 + threadIdx.x;
    if (e >= E) return;
    int d = dst[e];
    float ex = __expf(elog[e] - m[d]);
    atomicAdd(&denom[d], ex);
    int p = atomicAdd(&cursor[d], 1);
    srcs_s[p] = src[e];
    wsort[p]  = ex;
}

// final: one block per dst node, accumulate alpha * z[src]
__global__ __launch_bounds__(256) void k_out(const float* __restrict__ z,
                                             const int* __restrict__ offsets,
                                             const int* __restrict__ srcs_s,
                                             const float* __restrict__ wsort,
                                             const float* __restrict__ denom,
                                             float* __restrict__ out, int N){
    int n = blockIdx.x;
    int t = threadIdx.x;
    int i0 = offsets[n], i1 = offsets[n+1];
    float acc0 = 0.f, acc1 = 0.f;
    int i = i0;
    for (; i + 1 < i1; i += 2){
        float w0 = wsort[i],   w1 = wsort[i+1];
        int   s0 = srcs_s[i],  s1 = srcs_s[i+1];
        acc0 += w0 * z[s0*FDIM + t];
        acc1 += w1 * z[s1*FDIM + t];
    }
    if (i < i1){
        acc0 += wsort[i] * z[srcs_s[i]*FDIM + t];
    }
    float res = (i1 > i0) ? (acc0 + acc1) / denom[n] : 0.f;
    out[n*FDIM + t] = res;
}

extern "C" void kernel_launch(void* const* d_in, const int* in_sizes, int n_in,
                              void* d_out, int out_size, void* d_ws, size_t ws_size,
                              hipStream_t stream){
    const float* h  = (const float*)d_in[0];
    const float* ef = (const float*)d_in[1];
    const float* W  = (const float*)d_in[2];
    const float* A  = (const float*)d_in[3];
    const int*  src = (const int*)d_in[4];
    const int*  dst = (const int*)d_in[5];
    float* out = (float*)d_out;
    int N = in_sizes[0] / FDIM;
    int E = in_sizes[4];

    char* ws = (char*)d_ws;
    size_t off = 0;
    auto alloc = [&](size_t nbytes)->char*{
        char* p = ws + off;
        off = (off + nbytes + 255) & ~(size_t)255;
        return p;
    };
    float* z      = (float*)alloc((size_t)N*FDIM*4);
    float* s_src  = (float*)alloc((size_t)N*4);
    float* s_dst  = (float*)alloc((size_t)N*4);
    float* mbuf   = (float*)alloc((size_t)N*4);
    float* denom  = (float*)alloc((size_t)N*4);
    float* elog   = (float*)alloc((size_t)E*4);
    int*   counts = (int*)alloc((size_t)(N+1)*4);
    int*   cursor = (int*)alloc((size_t)N*4);
    int*   srcs_s = (int*)alloc((size_t)E*4);
    float* wsort  = (float*)alloc((size_t)E*4);
    int*   bsums  = (int*)alloc(1024*4);

    int nb = (N + 1023)/1024;

    hipLaunchKernelGGL(k_init, dim3((N+255)/256), dim3(256), 0, stream,
                       mbuf, denom, counts, N);
    hipLaunchKernelGGL(k_gemm, dim3((N+BM-1)/BM, FDIM/BN), dim3(256), 0, stream,
                       h, W, z, N);
    hipLaunchKernelGGL(k_sdots, dim3((N+3)/4), dim3(256), 0, stream,
                       z, A, s_src, s_dst, N);
    hipLaunchKernelGGL(k_edge, dim3((E+15)/16), dim3(256), 0, stream,
                       ef, A, s_src, s_dst, src, dst, elog, mbuf, counts, E);
    hipLaunchKernelGGL(k_chunk_sums, dim3(nb), dim3(256), 0, stream,
                       counts, bsums, N);
    hipLaunchKernelGGL(k_scan_small, dim3(1), dim3(1024), 0, stream,
                       bsums, nb);
    hipLaunchKernelGGL(k_scan_chunks, dim3(nb), dim3(256), 0, stream,
                       counts, cursor, bsums, N, E);
    hipLaunchKernelGGL(k_scatter, dim3((E+255)/256), dim3(256), 0, stream,
                       elog, mbuf, src, dst, denom, cursor, srcs_s, wsort, E);
    hipLaunchKernelGGL(k_out, dim3(N), dim3(256), 0, stream,
                       z, counts, srcs_s, wsort, denom, out, N);
}

// Round 4
// 321.176 us; speedup vs baseline: 1.3080x; 1.1034x over previous
//
#include <hip/hip_runtime.h>
#include <hip/hip_bf16.h>

#define FDIM 256
#define EDIM 64
#define LEAKY 0.2f

// MFMA GEMM tiling
#define BM 128
#define BN 128
#define BK 32

typedef __attribute__((ext_vector_type(8))) short bfrag;   // 8 bf16 = 4 VGPR
typedef __attribute__((ext_vector_type(4))) float f4acc;   // 4 f32 accum

// fp32 -> bf16 bits, round-to-nearest-even
__device__ __forceinline__ unsigned f2bf(float x){
    unsigned u = __float_as_uint(x);
    return (u + 0x7FFFu + ((u >> 16) & 1u)) >> 16;
}
// exact float value of a bf16 bit pattern
__device__ __forceinline__ float bf2f(unsigned b){
    return __uint_as_float(b << 16);
}
__device__ __forceinline__ unsigned pack_hi(float x, float y, float& hx, float& hy){
    unsigned bx = f2bf(x), by = f2bf(y);
    hx = bf2f(bx); hy = bf2f(by);
    return bx | (by << 16);
}
__device__ __forceinline__ unsigned pack_lo(float rx, float ry){
    return f2bf(rx) | (f2bf(ry) << 16);
}

__device__ __forceinline__ void atomic_max_float(float* addr, float val){
    if (val >= 0.f) atomicMax((int*)addr, __float_as_int(val));
    else            atomicMin((unsigned int*)addr, (unsigned int)__float_as_int(val));
}

__global__ void k_init(float* __restrict__ m, float* __restrict__ denom,
                       int* __restrict__ counts, int N){
    int i = blockIdx.x*256 + threadIdx.x;
    if (i < N){ m[i] = -3.402823466e38f; denom[i] = 0.f; counts[i] = 0; }
}

// z = h @ W^T via split-bf16 MFMA: A = hi+lo, B = hi only.
// acc += Ah*Bh + Al*Bh   (A*Bl and Al*Bl dropped: ~2^-9 relative, within tol)
// Output written as bf16 (z16).
__global__ __launch_bounds__(256, 2) void k_gemm(const float* __restrict__ h,
                                                 const float* __restrict__ W,
                                                 unsigned short* __restrict__ z16, int M){
    // LDS per row: 8 slots of uint4; A: hi at slot k8^(row&7), lo at ^4.
    // B: hi only at slot k8^(row&7) (lo slots unused).
    __shared__ uint4 smA[BM*8];
    __shared__ uint4 smB[BN*8];

    int tid = threadIdx.x;
    int m0 = blockIdx.x * BM;
    int n0 = blockIdx.y * BN;

    int wid  = tid >> 6;
    int lane = tid & 63;
    int wm = (wid >> 1) * 64;   // wave m-offset in tile
    int wn = (wid & 1) * 64;    // wave n-offset in tile
    int l15 = lane & 15;
    int l4  = lane >> 4;

    f4acc acc[4][4];
    #pragma unroll
    for (int i = 0; i < 4; ++i)
        #pragma unroll
        for (int j = 0; j < 4; ++j)
            acc[i][j] = (f4acc)(0.f);

    for (int kc = 0; kc < FDIM; kc += BK){
        // ---- stage: 1024 (row,k8) items, 4 per thread
        #pragma unroll
        for (int q = 0; q < 4; ++q){
            int p = tid + q*256;          // 0..511 = A (hi+lo), 512..1023 = B (hi)
            int isB = p >= 512;
            int pp = p & 511;
            int row = pp >> 2, k8 = pp & 3;
            float4 v0, v1;
            if (isB){
                const float* g = &W[(n0 + row)*FDIM + kc + k8*8];
                v0 = *(const float4*)g; v1 = *(const float4*)(g + 4);
            } else {
                int gr = m0 + row;
                if (gr < M){
                    const float* g = &h[gr*FDIM + kc + k8*8];
                    v0 = *(const float4*)g; v1 = *(const float4*)(g + 4);
                } else {
                    v0 = make_float4(0.f,0.f,0.f,0.f); v1 = v0;
                }
            }
            int sh = k8 ^ (row & 7);
            if (isB){
                uint4 hi; float hx, hy;
                hi.x = pack_hi(v0.x, v0.y, hx, hy);
                hi.y = pack_hi(v0.z, v0.w, hx, hy);
                hi.z = pack_hi(v1.x, v1.y, hx, hy);
                hi.w = pack_hi(v1.z, v1.w, hx, hy);
                smB[row*8 + sh] = hi;
            } else {
                uint4 hi, lo; float hx, hy;
                hi.x = pack_hi(v0.x, v0.y, hx, hy);
                lo.x = pack_lo(v0.x - hx, v0.y - hy);
                hi.y = pack_hi(v0.z, v0.w, hx, hy);
                lo.y = pack_lo(v0.z - hx, v0.w - hy);
                hi.z = pack_hi(v1.x, v1.y, hx, hy);
                lo.z = pack_lo(v1.x - hx, v1.w == v1.w ? v1.y - hy : 0.f); // placeholder avoided below
                // (recompute correctly)
                hi.z = pack_hi(v1.x, v1.y, hx, hy);
                lo.z = pack_lo(v1.x - hx, v1.y - hy);
                hi.w = pack_hi(v1.z, v1.w, hx, hy);
                lo.w = pack_lo(v1.z - hx, v1.w - hy);
                smA[row*8 + sh]       = hi;
                smA[row*8 + (sh ^ 4)] = lo;
            }
        }
        __syncthreads();

        // ---- compute: per wave 4x4 fragments of 16x16, 2 MFMA each
        bfrag ah[4], al[4];
        #pragma unroll
        for (int mf = 0; mf < 4; ++mf){
            int row = wm + mf*16 + l15;
            int sh = l4 ^ (row & 7);
            ah[mf] = *(const bfrag*)&smA[row*8 + sh];
            al[mf] = *(const bfrag*)&smA[row*8 + (sh ^ 4)];
        }
        #pragma unroll
        for (int nf = 0; nf < 4; ++nf){
            int row = wn + nf*16 + l15;
            int sh = l4 ^ (row & 7);
            bfrag bh = *(const bfrag*)&smB[row*8 + sh];
            #pragma unroll
            for (int mf = 0; mf < 4; ++mf){
                acc[mf][nf] = __builtin_amdgcn_mfma_f32_16x16x32_bf16(ah[mf], bh, acc[mf][nf], 0, 0, 0);
                acc[mf][nf] = __builtin_amdgcn_mfma_f32_16x16x32_bf16(al[mf], bh, acc[mf][nf], 0, 0, 0);
            }
        }
        __syncthreads();
    }

    // ---- epilogue: C/D layout col=lane&15, row=(lane>>4)*4+reg; write bf16
    #pragma unroll
    for (int mf = 0; mf < 4; ++mf){
        #pragma unroll
        for (int nf = 0; nf < 4; ++nf){
            int gcol = n0 + wn + nf*16 + l15;
            #pragma unroll
            for (int r = 0; r < 4; ++r){
                int grow = m0 + wm + mf*16 + l4*4 + r;
                if (grow < M)
                    z16[(size_t)grow*FDIM + gcol] = (unsigned short)f2bf(acc[mf][nf][r]);
            }
        }
    }
}

// per-node s_src, s_dst (one 64-lane wave per node, bf16 z)
__global__ void k_sdots(const unsigned short* __restrict__ z16, const float* __restrict__ A,
                        float* __restrict__ s_src, float* __restrict__ s_dst, int N){
    int gt = blockIdx.x*256 + threadIdx.x;
    int w = gt >> 6, lane = gt & 63;
    if (w >= N) return;
    uint2 raw = *(const uint2*)&z16[(size_t)w*FDIM + lane*4];
    float z0 = bf2f(raw.x & 0xffffu), z1 = bf2f(raw.x >> 16);
    float z2 = bf2f(raw.y & 0xffffu), z3 = bf2f(raw.y >> 16);
    float4 as = *(const float4*)&A[lane*4];
    float4 ad = *(const float4*)&A[FDIM + lane*4];
    float vs = z0*as.x + z1*as.y + z2*as.z + z3*as.w;
    float vd = z0*ad.x + z1*ad.y + z2*ad.z + z3*ad.w;
    #pragma unroll
    for (int o = 32; o > 0; o >>= 1){
        vs += __shfl_xor(vs, o);
        vd += __shfl_xor(vd, o);
    }
    if (lane == 0){ s_src[w] = vs; s_dst[w] = vd; }
}

// per-edge logits + leaky relu + segment-max + degree histogram (16 lanes/edge)
__global__ void k_edge(const float* __restrict__ ef, const float* __restrict__ A,
                       const float* __restrict__ s_src, const float* __restrict__ s_dst,
                       const int* __restrict__ src, const int* __restrict__ dst,
                       float* __restrict__ elog, float* __restrict__ m,
                       int* __restrict__ counts, int E){
    int gt = blockIdx.x*256 + threadIdx.x;
    int e = gt >> 4, l4 = gt & 15;
    if (e >= E) return;
    float4 f  = *(const float4*)&ef[(size_t)e*EDIM + l4*4];
    float4 ae = *(const float4*)&A[2*FDIM + l4*4];
    float v = f.x*ae.x + f.y*ae.y + f.z*ae.z + f.w*ae.w;
    v += __shfl_xor(v, 8); v += __shfl_xor(v, 4);
    v += __shfl_xor(v, 2); v += __shfl_xor(v, 1);
    if (l4 == 0){
        int d = dst[e];
        float lg = v + s_src[src[e]] + s_dst[d];
        lg = lg > 0.f ? lg : LEAKY*lg;
        elog[e] = lg;
        atomic_max_float(&m[d], lg);
        atomicAdd(&counts[d], 1);
    }
}

// scan phase 1: per-1024-chunk sums
__global__ void k_chunk_sums(const int* __restrict__ counts, int* __restrict__ bsums, int N){
    __shared__ int sh[256];
    int base = blockIdx.x*1024;
    int s = 0;
    for (int i = threadIdx.x; i < 1024; i += 256){
        int idx = base + i;
        s += (idx < N) ? counts[idx] : 0;
    }
    sh[threadIdx.x] = s; __syncthreads();
    for (int o = 128; o > 0; o >>= 1){
        if (threadIdx.x < o) sh[threadIdx.x] += sh[threadIdx.x + o];
        __syncthreads();
    }
    if (threadIdx.x == 0) bsums[blockIdx.x] = sh[0];
}

// scan phase 2: exclusive scan of chunk sums (nb <= 1024), single block
__global__ void k_scan_small(int* __restrict__ b, int nb){
    __shared__ int sh[1024];
    int tid = threadIdx.x;
    int v = (tid < nb) ? b[tid] : 0;
    sh[tid] = v; __syncthreads();
    int acc = v;
    for (int o = 1; o < 1024; o <<= 1){
        int t = (tid >= o) ? sh[tid - o] : 0;
        __syncthreads();
        acc += t; sh[tid] = acc;
        __syncthreads();
    }
    if (tid < nb) b[tid] = acc - v;
}

// scan phase 3: per-chunk exclusive scan -> offsets (in place) + cursor copy
__global__ void k_scan_chunks(int* __restrict__ counts, int* __restrict__ cursor,
                              const int* __restrict__ bsums, int N, int E){
    __shared__ int sh[256];
    int tid = threadIdx.x;
    int base = blockIdx.x*1024 + tid*4;
    int v[4]; int s = 0;
    #pragma unroll
    for (int l = 0; l < 4; l++){
        int idx = base + l;
        v[l] = (idx < N) ? counts[idx] : 0;
        s += v[l];
    }
    sh[tid] = s; __syncthreads();
    int acc = s;
    for (int o = 1; o < 256; o <<= 1){
        int t = (tid >= o) ? sh[tid - o] : 0;
        __syncthreads();
        acc += t; sh[tid] = acc;
        __syncthreads();
    }
    int excl = acc - s + bsums[blockIdx.x];
    #pragma unroll
    for (int l = 0; l < 4; l++){
        int idx = base + l;
        if (idx < N){ counts[idx] = excl; cursor[idx] = excl; }
        excl += v[l];
    }
    if (blockIdx.x == 0 && tid == 0) counts[N] = E;
}

// exp + denom accumulation + counting-sort scatter (packed {src, w} pairs)
__global__ void k_scatter(const float* __restrict__ elog, const float* __restrict__ m,
                          const int* __restrict__ src, const int* __restrict__ dst,
                          float* __restrict__ denom, int* __restrict__ cursor,
                          int2* __restrict__ epair, int E){
    int e = blockIdx.x*256 + threadIdx.x;
    if (e >= E) return;
    int d = dst[e];
    float ex = __expf(elog[e] - m[d]);
    atomicAdd(&denom[d], ex);
    int p = atomicAdd(&cursor[d], 1);
    int2 pr; pr.x = src[e]; pr.y = __float_as_int(ex);
    epair[p] = pr;
}

// final: 2 dst nodes per block, 128 threads/node, col-pair per thread, bf16 z gather
__global__ __launch_bounds__(256) void k_out(const unsigned short* __restrict__ z16,
                                             const int* __restrict__ offsets,
                                             const int2* __restrict__ epair,
                                             const float* __restrict__ denom,
                                             float* __restrict__ out, int N){
    int half = threadIdx.x >> 7;
    int tc   = threadIdx.x & 127;     // col pair index
    int n = blockIdx.x*2 + half;
    if (n >= N) return;
    int i0 = offsets[n], i1 = offsets[n+1];
    float a0 = 0.f, a1 = 0.f, b0 = 0.f, b1 = 0.f;
    int i = i0;
    for (; i + 1 < i1; i += 2){
        int2 p0 = epair[i], p1 = epair[i+1];
        unsigned r0 = *(const unsigned*)&z16[(size_t)p0.x*FDIM + tc*2];
        unsigned r1 = *(const unsigned*)&z16[(size_t)p1.x*FDIM + tc*2];
        float w0 = __int_as_float(p0.y), w1 = __int_as_float(p1.y);
        a0 += w0 * bf2f(r0 & 0xffffu);
        a1 += w0 * bf2f(r0 >> 16);
        b0 += w1 * bf2f(r1 & 0xffffu);
        b1 += w1 * bf2f(r1 >> 16);
    }
    if (i < i1){
        int2 p0 = epair[i];
        unsigned r0 = *(const unsigned*)&z16[(size_t)p0.x*FDIM + tc*2];
        float w0 = __int_as_float(p0.y);
        a0 += w0 * bf2f(r0 & 0xffffu);
        a1 += w0 * bf2f(r0 >> 16);
    }
    float inv = (i1 > i0) ? 1.f / denom[n] : 0.f;
    float2 res; res.x = (a0 + b0) * inv; res.y = (a1 + b1) * inv;
    *(float2*)&out[(size_t)n*FDIM + tc*2] = res;
}

extern "C" void kernel_launch(void* const* d_in, const int* in_sizes, int n_in,
                              void* d_out, int out_size, void* d_ws, size_t ws_size,
                              hipStream_t stream){
    const float* h  = (const float*)d_in[0];
    const float* ef = (const float*)d_in[1];
    const float* W  = (const float*)d_in[2];
    const float* A  = (const float*)d_in[3];
    const int*  src = (const int*)d_in[4];
    const int*  dst = (const int*)d_in[5];
    float* out = (float*)d_out;
    int N = in_sizes[0] / FDIM;
    int E = in_sizes[4];

    char* ws = (char*)d_ws;
    size_t off = 0;
    auto alloc = [&](size_t nbytes)->char*{
        char* p = ws + off;
        off = (off + nbytes + 255) & ~(size_t)255;
        return p;
    };
    unsigned short* z16 = (unsigned short*)alloc((size_t)N*FDIM*2);
    float* s_src  = (float*)alloc((size_t)N*4);
    float* s_dst  = (float*)alloc((size_t)N*4);
    float* mbuf   = (float*)alloc((size_t)N*4);
    float* denom  = (float*)alloc((size_t)N*4);
    float* elog   = (float*)alloc((size_t)E*4);
    int*   counts = (int*)alloc((size_t)(N+1)*4);
    int*   cursor = (int*)alloc((size_t)N*4);
    int2*  epair  = (int2*)alloc((size_t)E*8);
    int*   bsums  = (int*)alloc(1024*4);

    int nb = (N + 1023)/1024;

    hipLaunchKernelGGL(k_init, dim3((N+255)/256), dim3(256), 0, stream,
                       mbuf, denom, counts, N);
    hipLaunchKernelGGL(k_gemm, dim3((N+BM-1)/BM, FDIM/BN), dim3(256), 0, stream,
                       h, W, z16, N);
    hipLaunchKernelGGL(k_sdots, dim3((N+3)/4), dim3(256), 0, stream,
                       z16, A, s_src, s_dst, N);
    hipLaunchKernelGGL(k_edge, dim3((E+15)/16), dim3(256), 0, stream,
                       ef, A, s_src, s_dst, src, dst, elog, mbuf, counts, E);
    hipLaunchKernelGGL(k_chunk_sums, dim3(nb), dim3(256), 0, stream,
                       counts, bsums, N);
    hipLaunchKernelGGL(k_scan_small, dim3(1), dim3(1024), 0, stream,
                       bsums, nb);
    hipLaunchKernelGGL(k_scan_chunks, dim3(nb), dim3(256), 0, stream,
                       counts, cursor, bsums, N, E);
    hipLaunchKernelGGL(k_scatter, dim3((E+255)/256), dim3(256), 0, stream,
                       elog, mbuf, src, dst, denom, cursor, epair, E);
    hipLaunchKernelGGL(k_out, dim3((N+1)/2), dim3(256), 0, stream,
                       z16, counts, epair, denom, out, N);
}

// Round 5
// 242.225 us; speedup vs baseline: 1.7343x; 1.3259x over previous
//
#include <hip/hip_runtime.h>
#include <hip/hip_bf16.h>

#define FDIM 256
#define EDIM 64
#define LEAKY 0.2f

// MFMA GEMM tiling
#define BM 128
#define BN 128
#define BK 32

typedef __attribute__((ext_vector_type(8))) short bfrag;   // 8 bf16 = 4 VGPR
typedef __attribute__((ext_vector_type(4))) float f4acc;   // 4 f32 accum

// fp32 -> bf16 bits, round-to-nearest-even
__device__ __forceinline__ unsigned f2bf(float x){
    unsigned u = __float_as_uint(x);
    return (u + 0x7FFFu + ((u >> 16) & 1u)) >> 16;
}
// exact float value of a bf16 bit pattern
__device__ __forceinline__ float bf2f(unsigned b){
    return __uint_as_float(b << 16);
}
__device__ __forceinline__ unsigned pack_hi(float x, float y, float& hx, float& hy){
    unsigned bx = f2bf(x), by = f2bf(y);
    hx = bf2f(bx); hy = bf2f(by);
    return bx | (by << 16);
}
__device__ __forceinline__ unsigned pack_lo(float rx, float ry){
    return f2bf(rx) | (f2bf(ry) << 16);
}

__global__ void k_init(int* __restrict__ counts, int N){
    int i = blockIdx.x*256 + threadIdx.x;
    if (i < N) counts[i] = 0;
}

// z = h @ W^T via split-bf16 MFMA: A = hi+lo, B = hi only.
// acc += Ah*Bh + Al*Bh  (~2^-9 relative err, within tol). Output bf16.
__global__ __launch_bounds__(256, 2) void k_gemm(const float* __restrict__ h,
                                                 const float* __restrict__ W,
                                                 unsigned short* __restrict__ z16, int M){
    __shared__ uint4 smA[BM*8];
    __shared__ uint4 smB[BN*8];

    int tid = threadIdx.x;
    int m0 = blockIdx.x * BM;
    int n0 = blockIdx.y * BN;

    int wid  = tid >> 6;
    int lane = tid & 63;
    int wm = (wid >> 1) * 64;
    int wn = (wid & 1) * 64;
    int l15 = lane & 15;
    int l4  = lane >> 4;

    f4acc acc[4][4];
    #pragma unroll
    for (int i = 0; i < 4; ++i)
        #pragma unroll
        for (int j = 0; j < 4; ++j)
            acc[i][j] = (f4acc)(0.f);

    for (int kc = 0; kc < FDIM; kc += BK){
        #pragma unroll
        for (int q = 0; q < 4; ++q){
            int p = tid + q*256;          // 0..511 = A (hi+lo), 512..1023 = B (hi)
            int isB = p >= 512;
            int pp = p & 511;
            int row = pp >> 2, k8 = pp & 3;
            float4 v0, v1;
            if (isB){
                const float* g = &W[(n0 + row)*FDIM + kc + k8*8];
                v0 = *(const float4*)g; v1 = *(const float4*)(g + 4);
            } else {
                int gr = m0 + row;
                if (gr < M){
                    const float* g = &h[(size_t)gr*FDIM + kc + k8*8];
                    v0 = *(const float4*)g; v1 = *(const float4*)(g + 4);
                } else {
                    v0 = make_float4(0.f,0.f,0.f,0.f); v1 = v0;
                }
            }
            int sh = k8 ^ (row & 7);
            if (isB){
                uint4 hi; float hx, hy;
                hi.x = pack_hi(v0.x, v0.y, hx, hy);
                hi.y = pack_hi(v0.z, v0.w, hx, hy);
                hi.z = pack_hi(v1.x, v1.y, hx, hy);
                hi.w = pack_hi(v1.z, v1.w, hx, hy);
                smB[row*8 + sh] = hi;
            } else {
                uint4 hi, lo; float hx, hy;
                hi.x = pack_hi(v0.x, v0.y, hx, hy);
                lo.x = pack_lo(v0.x - hx, v0.y - hy);
                hi.y = pack_hi(v0.z, v0.w, hx, hy);
                lo.y = pack_lo(v0.z - hx, v0.w - hy);
                hi.z = pack_hi(v1.x, v1.y, hx, hy);
                lo.z = pack_lo(v1.x - hx, v1.y - hy);
                hi.w = pack_hi(v1.z, v1.w, hx, hy);
                lo.w = pack_lo(v1.z - hx, v1.w - hy);
                smA[row*8 + sh]       = hi;
                smA[row*8 + (sh ^ 4)] = lo;
            }
        }
        __syncthreads();

        bfrag ah[4], al[4];
        #pragma unroll
        for (int mf = 0; mf < 4; ++mf){
            int row = wm + mf*16 + l15;
            int sh = l4 ^ (row & 7);
            ah[mf] = *(const bfrag*)&smA[row*8 + sh];
            al[mf] = *(const bfrag*)&smA[row*8 + (sh ^ 4)];
        }
        #pragma unroll
        for (int nf = 0; nf < 4; ++nf){
            int row = wn + nf*16 + l15;
            int sh = l4 ^ (row & 7);
            bfrag bh = *(const bfrag*)&smB[row*8 + sh];
            #pragma unroll
            for (int mf = 0; mf < 4; ++mf){
                acc[mf][nf] = __builtin_amdgcn_mfma_f32_16x16x32_bf16(ah[mf], bh, acc[mf][nf], 0, 0, 0);
                acc[mf][nf] = __builtin_amdgcn_mfma_f32_16x16x32_bf16(al[mf], bh, acc[mf][nf], 0, 0, 0);
            }
        }
        __syncthreads();
    }

    #pragma unroll
    for (int mf = 0; mf < 4; ++mf){
        #pragma unroll
        for (int nf = 0; nf < 4; ++nf){
            int gcol = n0 + wn + nf*16 + l15;
            #pragma unroll
            for (int r = 0; r < 4; ++r){
                int grow = m0 + wm + mf*16 + l4*4 + r;
                if (grow < M)
                    z16[(size_t)grow*FDIM + gcol] = (unsigned short)f2bf(acc[mf][nf][r]);
            }
        }
    }
}

// per-node s_src, s_dst (one 64-lane wave per node, bf16 z)
__global__ void k_sdots(const unsigned short* __restrict__ z16, const float* __restrict__ A,
                        float* __restrict__ s_src, float* __restrict__ s_dst, int N){
    int gt = blockIdx.x*256 + threadIdx.x;
    int w = gt >> 6, lane = gt & 63;
    if (w >= N) return;
    uint2 raw = *(const uint2*)&z16[(size_t)w*FDIM + lane*4];
    float z0 = bf2f(raw.x & 0xffffu), z1 = bf2f(raw.x >> 16);
    float z2 = bf2f(raw.y & 0xffffu), z3 = bf2f(raw.y >> 16);
    float4 as = *(const float4*)&A[lane*4];
    float4 ad = *(const float4*)&A[FDIM + lane*4];
    float vs = z0*as.x + z1*as.y + z2*as.z + z3*as.w;
    float vd = z0*ad.x + z1*ad.y + z2*ad.z + z3*ad.w;
    #pragma unroll
    for (int o = 32; o > 0; o >>= 1){
        vs += __shfl_xor(vs, o);
        vd += __shfl_xor(vd, o);
    }
    if (lane == 0){ s_src[w] = vs; s_dst[w] = vd; }
}

// degree histogram
__global__ void k_count(const int* __restrict__ dst, int* __restrict__ counts, int E){
    int e = blockIdx.x*256 + threadIdx.x;
    if (e < E) atomicAdd(&counts[dst[e]], 1);
}

// scan phase 1: per-1024-chunk sums
__global__ void k_chunk_sums(const int* __restrict__ counts, int* __restrict__ bsums, int N){
    __shared__ int sh[256];
    int base = blockIdx.x*1024;
    int s = 0;
    for (int i = threadIdx.x; i < 1024; i += 256){
        int idx = base + i;
        s += (idx < N) ? counts[idx] : 0;
    }
    sh[threadIdx.x] = s; __syncthreads();
    for (int o = 128; o > 0; o >>= 1){
        if (threadIdx.x < o) sh[threadIdx.x] += sh[threadIdx.x + o];
        __syncthreads();
    }
    if (threadIdx.x == 0) bsums[blockIdx.x] = sh[0];
}

// scan phase 2: exclusive scan of chunk sums (nb <= 1024), single block
__global__ void k_scan_small(int* __restrict__ b, int nb){
    __shared__ int sh[1024];
    int tid = threadIdx.x;
    int v = (tid < nb) ? b[tid] : 0;
    sh[tid] = v; __syncthreads();
    int acc = v;
    for (int o = 1; o < 1024; o <<= 1){
        int t = (tid >= o) ? sh[tid - o] : 0;
        __syncthreads();
        acc += t; sh[tid] = acc;
        __syncthreads();
    }
    if (tid < nb) b[tid] = acc - v;
}

// scan phase 3: per-chunk exclusive scan -> offsets (in place) + cursor copy
__global__ void k_scan_chunks(int* __restrict__ counts, int* __restrict__ cursor,
                              const int* __restrict__ bsums, int N, int E){
    __shared__ int sh[256];
    int tid = threadIdx.x;
    int base = blockIdx.x*1024 + tid*4;
    int v[4]; int s = 0;
    #pragma unroll
    for (int l = 0; l < 4; l++){
        int idx = base + l;
        v[l] = (idx < N) ? counts[idx] : 0;
        s += v[l];
    }
    sh[tid] = s; __syncthreads();
    int acc = s;
    for (int o = 1; o < 256; o <<= 1){
        int t = (tid >= o) ? sh[tid - o] : 0;
        __syncthreads();
        acc += t; sh[tid] = acc;
        __syncthreads();
    }
    int excl = acc - s + bsums[blockIdx.x];
    #pragma unroll
    for (int l = 0; l < 4; l++){
        int idx = base + l;
        if (idx < N){ counts[idx] = excl; cursor[idx] = excl; }
        excl += v[l];
    }
    if (blockIdx.x == 0 && tid == 0) counts[N] = E;
}

// per-edge: e_feat dot + logit + leaky-relu + counting-sort write {src, logit}
__global__ void k_edge(const float* __restrict__ ef, const float* __restrict__ A,
                       const float* __restrict__ s_src, const float* __restrict__ s_dst,
                       const int* __restrict__ src, const int* __restrict__ dst,
                       int* __restrict__ cursor, int2* __restrict__ epair, int E){
    int gt = blockIdx.x*256 + threadIdx.x;
    int e = gt >> 4, l4 = gt & 15;
    if (e >= E) return;
    float4 f  = *(const float4*)&ef[(size_t)e*EDIM + l4*4];
    float4 ae = *(const float4*)&A[2*FDIM + l4*4];
    float v = f.x*ae.x + f.y*ae.y + f.z*ae.z + f.w*ae.w;
    v += __shfl_xor(v, 8); v += __shfl_xor(v, 4);
    v += __shfl_xor(v, 2); v += __shfl_xor(v, 1);
    if (l4 == 0){
        int d = dst[e];
        float lg = v + s_src[src[e]] + s_dst[d];
        lg = lg > 0.f ? lg : LEAKY*lg;
        int p = atomicAdd(&cursor[d], 1);
        int2 pr; pr.x = src[e]; pr.y = __float_as_int(lg);
        epair[p] = pr;
    }
}

// final: 4 dst nodes per block, one 64-lane wave per node, local softmax + gather
__global__ __launch_bounds__(256) void k_out(const unsigned short* __restrict__ z16,
                                             const int* __restrict__ offsets,
                                             const int2* __restrict__ epair,
                                             float* __restrict__ out, int N){
    int n = blockIdx.x*4 + (threadIdx.x >> 6);
    int lane = threadIdx.x & 63;
    if (n >= N) return;
    int i0 = offsets[n], i1 = offsets[n+1];

    // pass 1: max logit (redundant per lane; epair reads broadcast)
    float mx = -3.402823466e38f;
    for (int i = i0; i < i1; ++i)
        mx = fmaxf(mx, __int_as_float(epair[i].y));

    // pass 2: exp-weighted gather, 4-edge unroll, independent accumulators
    float4 a0 = make_float4(0,0,0,0), a1 = a0, a2 = a0, a3 = a0;
    float ds0 = 0.f, ds1 = 0.f, ds2 = 0.f, ds3 = 0.f;
    const unsigned short* zb = z16 + lane*4;
    int i = i0;
    for (; i + 3 < i1; i += 4){
        int2 p0 = epair[i], p1 = epair[i+1], p2 = epair[i+2], p3 = epair[i+3];
        uint2 r0 = *(const uint2*)&zb[(size_t)p0.x*FDIM];
        uint2 r1 = *(const uint2*)&zb[(size_t)p1.x*FDIM];
        uint2 r2 = *(const uint2*)&zb[(size_t)p2.x*FDIM];
        uint2 r3 = *(const uint2*)&zb[(size_t)p3.x*FDIM];
        float w0 = __expf(__int_as_float(p0.y) - mx);
        float w1 = __expf(__int_as_float(p1.y) - mx);
        float w2 = __expf(__int_as_float(p2.y) - mx);
        float w3 = __expf(__int_as_float(p3.y) - mx);
        ds0 += w0; ds1 += w1; ds2 += w2; ds3 += w3;
        a0.x += w0*bf2f(r0.x & 0xffffu); a0.y += w0*bf2f(r0.x >> 16);
        a0.z += w0*bf2f(r0.y & 0xffffu); a0.w += w0*bf2f(r0.y >> 16);
        a1.x += w1*bf2f(r1.x & 0xffffu); a1.y += w1*bf2f(r1.x >> 16);
        a1.z += w1*bf2f(r1.y & 0xffffu); a1.w += w1*bf2f(r1.y >> 16);
        a2.x += w2*bf2f(r2.x & 0xffffu); a2.y += w2*bf2f(r2.x >> 16);
        a2.z += w2*bf2f(r2.y & 0xffffu); a2.w += w2*bf2f(r2.y >> 16);
        a3.x += w3*bf2f(r3.x & 0xffffu); a3.y += w3*bf2f(r3.x >> 16);
        a3.z += w3*bf2f(r3.y & 0xffffu); a3.w += w3*bf2f(r3.y >> 16);
    }
    for (; i < i1; ++i){
        int2 p0 = epair[i];
        uint2 r0 = *(const uint2*)&zb[(size_t)p0.x*FDIM];
        float w0 = __expf(__int_as_float(p0.y) - mx);
        ds0 += w0;
        a0.x += w0*bf2f(r0.x & 0xffffu); a0.y += w0*bf2f(r0.x >> 16);
        a0.z += w0*bf2f(r0.y & 0xffffu); a0.w += w0*bf2f(r0.y >> 16);
    }
    float dsum = (ds0 + ds1) + (ds2 + ds3);
    float inv = (i1 > i0) ? 1.f / dsum : 0.f;
    float4 res;
    res.x = ((a0.x + a1.x) + (a2.x + a3.x)) * inv;
    res.y = ((a0.y + a1.y) + (a2.y + a3.y)) * inv;
    res.z = ((a0.z + a1.z) + (a2.z + a3.z)) * inv;
    res.w = ((a0.w + a1.w) + (a2.w + a3.w)) * inv;
    *(float4*)&out[(size_t)n*FDIM + lane*4] = res;
}

extern "C" void kernel_launch(void* const* d_in, const int* in_sizes, int n_in,
                              void* d_out, int out_size, void* d_ws, size_t ws_size,
                              hipStream_t stream){
    const float* h  = (const float*)d_in[0];
    const float* ef = (const float*)d_in[1];
    const float* W  = (const float*)d_in[2];
    const float* A  = (const float*)d_in[3];
    const int*  src = (const int*)d_in[4];
    const int*  dst = (const int*)d_in[5];
    float* out = (float*)d_out;
    int N = in_sizes[0] / FDIM;
    int E = in_sizes[4];

    char* ws = (char*)d_ws;
    size_t off = 0;
    auto alloc = [&](size_t nbytes)->char*{
        char* p = ws + off;
        off = (off + nbytes + 255) & ~(size_t)255;
        return p;
    };
    unsigned short* z16 = (unsigned short*)alloc((size_t)N*FDIM*2);
    float* s_src  = (float*)alloc((size_t)N*4);
    float* s_dst  = (float*)alloc((size_t)N*4);
    int*   counts = (int*)alloc((size_t)(N+1)*4);
    int*   cursor = (int*)alloc((size_t)N*4);
    int2*  epair  = (int2*)alloc((size_t)E*8);
    int*   bsums  = (int*)alloc(1024*4);

    int nb = (N + 1023)/1024;

    hipLaunchKernelGGL(k_init, dim3((N+255)/256), dim3(256), 0, stream,
                       counts, N);
    hipLaunchKernelGGL(k_gemm, dim3((N+BM-1)/BM, FDIM/BN), dim3(256), 0, stream,
                       h, W, z16, N);
    hipLaunchKernelGGL(k_sdots, dim3((N+3)/4), dim3(256), 0, stream,
                       z16, A, s_src, s_dst, N);
    hipLaunchKernelGGL(k_count, dim3((E+255)/256), dim3(256), 0, stream,
                       dst, counts, E);
    hipLaunchKernelGGL(k_chunk_sums, dim3(nb), dim3(256), 0, stream,
                       counts, bsums, N);
    hipLaunchKernelGGL(k_scan_small, dim3(1), dim3(1024), 0, stream,
                       bsums, nb);
    hipLaunchKernelGGL(k_scan_chunks, dim3(nb), dim3(256), 0, stream,
                       counts, cursor, bsums, N, E);
    hipLaunchKernelGGL(k_edge, dim3((E+15)/16), dim3(256), 0, stream,
                       ef, A, s_src, s_dst, src, dst, cursor, epair, E);
    hipLaunchKernelGGL(k_out, dim3((N+3)/4), dim3(256), 0, stream,
                       z16, counts, epair, out, N);
}

// Round 6
// 237.273 us; speedup vs baseline: 1.7705x; 1.0209x over previous
//
#include <hip/hip_runtime.h>
#include <hip/hip_bf16.h>

#define FDIM 256
#define EDIM 64
#define LEAKY 0.2f

// MFMA GEMM tiling
#define BM 128
#define BN 128
#define BK 32

typedef __attribute__((ext_vector_type(8))) short bfrag;   // 8 bf16 = 4 VGPR
typedef __attribute__((ext_vector_type(4))) float f4acc;   // 4 f32 accum

// fp32 -> bf16 bits, round-to-nearest-even
__device__ __forceinline__ unsigned f2bf(float x){
    unsigned u = __float_as_uint(x);
    return (u + 0x7FFFu + ((u >> 16) & 1u)) >> 16;
}
// exact float value of a bf16 bit pattern
__device__ __forceinline__ float bf2f(unsigned b){
    return __uint_as_float(b << 16);
}
__device__ __forceinline__ unsigned pack_hi(float x, float y, float& hx, float& hy){
    unsigned bx = f2bf(x), by = f2bf(y);
    hx = bf2f(bx); hy = bf2f(by);
    return bx | (by << 16);
}
__device__ __forceinline__ unsigned pack_lo(float rx, float ry){
    return f2bf(rx) | (f2bf(ry) << 16);
}

__device__ __forceinline__ void atomic_max_float(float* addr, float val){
    if (val >= 0.f) atomicMax((int*)addr, __float_as_int(val));
    else            atomicMin((unsigned int*)addr, (unsigned int)__float_as_int(val));
}

__global__ void k_init(float* __restrict__ m, float* __restrict__ s_src,
                       float* __restrict__ s_dst, int* __restrict__ counts, int N){
    int i = blockIdx.x*256 + threadIdx.x;
    if (i < N){
        m[i] = -3.402823466e38f;
        s_src[i] = 0.f; s_dst[i] = 0.f;
        counts[i] = 0;
    }
}

// z = h @ W^T via split-bf16 MFMA: A = hi+lo, B = hi only.
// acc += Ah*Bh + Al*Bh  (~2^-9 relative err, within tol). Output bf16.
// Epilogue also computes partial s_src/s_dst = z-row . a_src/a_dst (this
// block's 128-col slice) and atomicAdds into the global vectors.
__global__ __launch_bounds__(256, 2) void k_gemm(const float* __restrict__ h,
                                                 const float* __restrict__ W,
                                                 const float* __restrict__ A,
                                                 unsigned short* __restrict__ z16,
                                                 float* __restrict__ s_src,
                                                 float* __restrict__ s_dst, int M){
    __shared__ uint4 smA[BM*8];
    __shared__ uint4 smB[BN*8];
    __shared__ float sred[2][2][BM];   // [wn-half][src/dst][row]

    int tid = threadIdx.x;
    int m0 = blockIdx.x * BM;
    int n0 = blockIdx.y * BN;

    int wid  = tid >> 6;
    int lane = tid & 63;
    int wm = (wid >> 1) * 64;
    int wn = (wid & 1) * 64;
    int l15 = lane & 15;
    int l4  = lane >> 4;

    f4acc acc[4][4];
    #pragma unroll
    for (int i = 0; i < 4; ++i)
        #pragma unroll
        for (int j = 0; j < 4; ++j)
            acc[i][j] = (f4acc)(0.f);

    for (int kc = 0; kc < FDIM; kc += BK){
        #pragma unroll
        for (int q = 0; q < 4; ++q){
            int p = tid + q*256;          // 0..511 = A (hi+lo), 512..1023 = B (hi)
            int isB = p >= 512;
            int pp = p & 511;
            int row = pp >> 2, k8 = pp & 3;
            float4 v0, v1;
            if (isB){
                const float* g = &W[(n0 + row)*FDIM + kc + k8*8];
                v0 = *(const float4*)g; v1 = *(const float4*)(g + 4);
            } else {
                int gr = m0 + row;
                if (gr < M){
                    const float* g = &h[(size_t)gr*FDIM + kc + k8*8];
                    v0 = *(const float4*)g; v1 = *(const float4*)(g + 4);
                } else {
                    v0 = make_float4(0.f,0.f,0.f,0.f); v1 = v0;
                }
            }
            int sh = k8 ^ (row & 7);
            if (isB){
                uint4 hi; float hx, hy;
                hi.x = pack_hi(v0.x, v0.y, hx, hy);
                hi.y = pack_hi(v0.z, v0.w, hx, hy);
                hi.z = pack_hi(v1.x, v1.y, hx, hy);
                hi.w = pack_hi(v1.z, v1.w, hx, hy);
                smB[row*8 + sh] = hi;
            } else {
                uint4 hi, lo; float hx, hy;
                hi.x = pack_hi(v0.x, v0.y, hx, hy);
                lo.x = pack_lo(v0.x - hx, v0.y - hy);
                hi.y = pack_hi(v0.z, v0.w, hx, hy);
                lo.y = pack_lo(v0.z - hx, v0.w - hy);
                hi.z = pack_hi(v1.x, v1.y, hx, hy);
                lo.z = pack_lo(v1.x - hx, v1.y - hy);
                hi.w = pack_hi(v1.z, v1.w, hx, hy);
                lo.w = pack_lo(v1.z - hx, v1.w - hy);
                smA[row*8 + sh]       = hi;
                smA[row*8 + (sh ^ 4)] = lo;
            }
        }
        __syncthreads();

        bfrag ah[4], al[4];
        #pragma unroll
        for (int mf = 0; mf < 4; ++mf){
            int row = wm + mf*16 + l15;
            int sh = l4 ^ (row & 7);
            ah[mf] = *(const bfrag*)&smA[row*8 + sh];
            al[mf] = *(const bfrag*)&smA[row*8 + (sh ^ 4)];
        }
        #pragma unroll
        for (int nf = 0; nf < 4; ++nf){
            int row = wn + nf*16 + l15;
            int sh = l4 ^ (row & 7);
            bfrag bh = *(const bfrag*)&smB[row*8 + sh];
            #pragma unroll
            for (int mf = 0; mf < 4; ++mf){
                acc[mf][nf] = __builtin_amdgcn_mfma_f32_16x16x32_bf16(ah[mf], bh, acc[mf][nf], 0, 0, 0);
                acc[mf][nf] = __builtin_amdgcn_mfma_f32_16x16x32_bf16(al[mf], bh, acc[mf][nf], 0, 0, 0);
            }
        }
        __syncthreads();
    }

    // ---- z write (bf16) ----
    #pragma unroll
    for (int mf = 0; mf < 4; ++mf){
        #pragma unroll
        for (int nf = 0; nf < 4; ++nf){
            int gcol = n0 + wn + nf*16 + l15;
            #pragma unroll
            for (int r = 0; r < 4; ++r){
                int grow = m0 + wm + mf*16 + l4*4 + r;
                if (grow < M)
                    z16[(size_t)grow*FDIM + gcol] = (unsigned short)f2bf(acc[mf][nf][r]);
            }
        }
    }

    // ---- fused partial s_src / s_dst ----
    float aS[4], aD[4];
    #pragma unroll
    for (int nf = 0; nf < 4; ++nf){
        int gcol = n0 + wn + nf*16 + l15;
        aS[nf] = A[gcol];
        aD[nf] = A[FDIM + gcol];
    }
    #pragma unroll
    for (int mf = 0; mf < 4; ++mf){
        #pragma unroll
        for (int r = 0; r < 4; ++r){
            float ps = 0.f, pd = 0.f;
            #pragma unroll
            for (int nf = 0; nf < 4; ++nf){
                ps += acc[mf][nf][r] * aS[nf];
                pd += acc[mf][nf][r] * aD[nf];
            }
            // reduce over l15 (16 cols per lane-group)
            #pragma unroll
            for (int o = 1; o < 16; o <<= 1){
                ps += __shfl_xor(ps, o);
                pd += __shfl_xor(pd, o);
            }
            if (l15 == 0){
                int row = wm + mf*16 + l4*4 + r;
                sred[wid & 1][0][row] = ps;
                sred[wid & 1][1][row] = pd;
            }
        }
    }
    __syncthreads();
    if (tid < BM){
        int grow = m0 + tid;
        if (grow < M){
            atomicAdd(&s_src[grow], sred[0][0][tid] + sred[1][0][tid]);
            atomicAdd(&s_dst[grow], sred[0][1][tid] + sred[1][1][tid]);
        }
    }
}

// degree histogram
__global__ void k_count(const int* __restrict__ dst, int* __restrict__ counts, int E){
    int e = blockIdx.x*256 + threadIdx.x;
    if (e < E) atomicAdd(&counts[dst[e]], 1);
}

// scan phase 1: per-1024-chunk sums
__global__ void k_chunk_sums(const int* __restrict__ counts, int* __restrict__ bsums, int N){
    __shared__ int sh[256];
    int base = blockIdx.x*1024;
    int s = 0;
    for (int i = threadIdx.x; i < 1024; i += 256){
        int idx = base + i;
        s += (idx < N) ? counts[idx] : 0;
    }
    sh[threadIdx.x] = s; __syncthreads();
    for (int o = 128; o > 0; o >>= 1){
        if (threadIdx.x < o) sh[threadIdx.x] += sh[threadIdx.x + o];
        __syncthreads();
    }
    if (threadIdx.x == 0) bsums[blockIdx.x] = sh[0];
}

// scan phase 2: exclusive scan of chunk sums (nb <= 1024), single block
__global__ void k_scan_small(int* __restrict__ b, int nb){
    __shared__ int sh[1024];
    int tid = threadIdx.x;
    int v = (tid < nb) ? b[tid] : 0;
    sh[tid] = v; __syncthreads();
    int acc = v;
    for (int o = 1; o < 1024; o <<= 1){
        int t = (tid >= o) ? sh[tid - o] : 0;
        __syncthreads();
        acc += t; sh[tid] = acc;
        __syncthreads();
    }
    if (tid < nb) b[tid] = acc - v;
}

// scan phase 3: per-chunk exclusive scan -> offsets (in place) + cursor copy
__global__ void k_scan_chunks(int* __restrict__ counts, int* __restrict__ cursor,
                              const int* __restrict__ bsums, int N, int E){
    __shared__ int sh[256];
    int tid = threadIdx.x;
    int base = blockIdx.x*1024 + tid*4;
    int v[4]; int s = 0;
    #pragma unroll
    for (int l = 0; l < 4; l++){
        int idx = base + l;
        v[l] = (idx < N) ? counts[idx] : 0;
        s += v[l];
    }
    sh[tid] = s; __syncthreads();
    int acc = s;
    for (int o = 1; o < 256; o <<= 1){
        int t = (tid >= o) ? sh[tid - o] : 0;
        __syncthreads();
        acc += t; sh[tid] = acc;
        __syncthreads();
    }
    int excl = acc - s + bsums[blockIdx.x];
    #pragma unroll
    for (int l = 0; l < 4; l++){
        int idx = base + l;
        if (idx < N){ counts[idx] = excl; cursor[idx] = excl; }
        excl += v[l];
    }
    if (blockIdx.x == 0 && tid == 0) counts[N] = E;
}

// per-edge: e_feat dot + logit + leaky-relu + segment max + counting-sort {src, logit}
__global__ void k_edge(const float* __restrict__ ef, const float* __restrict__ A,
                       const float* __restrict__ s_src, const float* __restrict__ s_dst,
                       const int* __restrict__ src, const int* __restrict__ dst,
                       float* __restrict__ m, int* __restrict__ cursor,
                       int2* __restrict__ epair, int E){
    int gt = blockIdx.x*256 + threadIdx.x;
    int e = gt >> 4, l4 = gt & 15;
    if (e >= E) return;
    float4 f  = *(const float4*)&ef[(size_t)e*EDIM + l4*4];
    float4 ae = *(const float4*)&A[2*FDIM + l4*4];
    float v = f.x*ae.x + f.y*ae.y + f.z*ae.z + f.w*ae.w;
    v += __shfl_xor(v, 8); v += __shfl_xor(v, 4);
    v += __shfl_xor(v, 2); v += __shfl_xor(v, 1);
    if (l4 == 0){
        int d = dst[e];
        float lg = v + s_src[src[e]] + s_dst[d];
        lg = lg > 0.f ? lg : LEAKY*lg;
        atomic_max_float(&m[d], lg);
        int p = atomicAdd(&cursor[d], 1);
        int2 pr; pr.x = src[e]; pr.y = __float_as_int(lg);
        epair[p] = pr;
    }
}

// final: 4 dst nodes per block, one 64-lane wave per node, single pass
// (max precomputed in m[]), 8-deep unroll for load ILP
__global__ __launch_bounds__(256) void k_out(const unsigned short* __restrict__ z16,
                                             const int* __restrict__ offsets,
                                             const int2* __restrict__ epair,
                                             const float* __restrict__ m,
                                             float* __restrict__ out, int N){
    int n = blockIdx.x*4 + (threadIdx.x >> 6);
    int lane = threadIdx.x & 63;
    if (n >= N) return;
    int i0 = offsets[n], i1 = offsets[n+1];
    float mx = m[n];

    float4 a[4];
    a[0] = make_float4(0,0,0,0); a[1] = a[0]; a[2] = a[0]; a[3] = a[0];
    float ds[4] = {0.f, 0.f, 0.f, 0.f};
    const unsigned short* zb = z16 + lane*4;

    int i = i0;
    for (; i + 7 < i1; i += 8){
        int2 p[8]; uint2 r[8];
        #pragma unroll
        for (int j = 0; j < 8; ++j) p[j] = epair[i+j];
        #pragma unroll
        for (int j = 0; j < 8; ++j) r[j] = *(const uint2*)&zb[(size_t)p[j].x*FDIM];
        #pragma unroll
        for (int j = 0; j < 8; ++j){
            float w = __expf(__int_as_float(p[j].y) - mx);
            ds[j & 3] += w;
            a[j & 3].x += w*bf2f(r[j].x & 0xffffu);
            a[j & 3].y += w*bf2f(r[j].x >> 16);
            a[j & 3].z += w*bf2f(r[j].y & 0xffffu);
            a[j & 3].w += w*bf2f(r[j].y >> 16);
        }
    }
    for (; i + 3 < i1; i += 4){
        int2 p[4]; uint2 r[4];
        #pragma unroll
        for (int j = 0; j < 4; ++j) p[j] = epair[i+j];
        #pragma unroll
        for (int j = 0; j < 4; ++j) r[j] = *(const uint2*)&zb[(size_t)p[j].x*FDIM];
        #pragma unroll
        for (int j = 0; j < 4; ++j){
            float w = __expf(__int_as_float(p[j].y) - mx);
            ds[j] += w;
            a[j].x += w*bf2f(r[j].x & 0xffffu);
            a[j].y += w*bf2f(r[j].x >> 16);
            a[j].z += w*bf2f(r[j].y & 0xffffu);
            a[j].w += w*bf2f(r[j].y >> 16);
        }
    }
    for (; i < i1; ++i){
        int2 p0 = epair[i];
        uint2 r0 = *(const uint2*)&zb[(size_t)p0.x*FDIM];
        float w = __expf(__int_as_float(p0.y) - mx);
        ds[0] += w;
        a[0].x += w*bf2f(r0.x & 0xffffu);
        a[0].y += w*bf2f(r0.x >> 16);
        a[0].z += w*bf2f(r0.y & 0xffffu);
        a[0].w += w*bf2f(r0.y >> 16);
    }
    float dsum = (ds[0] + ds[1]) + (ds[2] + ds[3]);
    float inv = (i1 > i0) ? 1.f / dsum : 0.f;
    float4 res;
    res.x = ((a[0].x + a[1].x) + (a[2].x + a[3].x)) * inv;
    res.y = ((a[0].y + a[1].y) + (a[2].y + a[3].y)) * inv;
    res.z = ((a[0].z + a[1].z) + (a[2].z + a[3].z)) * inv;
    res.w = ((a[0].w + a[1].w) + (a[2].w + a[3].w)) * inv;
    *(float4*)&out[(size_t)n*FDIM + lane*4] = res;
}

extern "C" void kernel_launch(void* const* d_in, const int* in_sizes, int n_in,
                              void* d_out, int out_size, void* d_ws, size_t ws_size,
                              hipStream_t stream){
    const float* h  = (const float*)d_in[0];
    const float* ef = (const float*)d_in[1];
    const float* W  = (const float*)d_in[2];
    const float* A  = (const float*)d_in[3];
    const int*  src = (const int*)d_in[4];
    const int*  dst = (const int*)d_in[5];
    float* out = (float*)d_out;
    int N = in_sizes[0] / FDIM;
    int E = in_sizes[4];

    char* ws = (char*)d_ws;
    size_t off = 0;
    auto alloc = [&](size_t nbytes)->char*{
        char* p = ws + off;
        off = (off + nbytes + 255) & ~(size_t)255;
        return p;
    };
    unsigned short* z16 = (unsigned short*)alloc((size_t)N*FDIM*2);
    float* s_src  = (float*)alloc((size_t)N*4);
    float* s_dst  = (float*)alloc((size_t)N*4);
    float* mbuf   = (float*)alloc((size_t)N*4);
    int*   counts = (int*)alloc((size_t)(N+1)*4);
    int*   cursor = (int*)alloc((size_t)N*4);
    int2*  epair  = (int2*)alloc((size_t)E*8);
    int*   bsums  = (int*)alloc(1024*4);

    int nb = (N + 1023)/1024;

    hipLaunchKernelGGL(k_init, dim3((N+255)/256), dim3(256), 0, stream,
                       mbuf, s_src, s_dst, counts, N);
    hipLaunchKernelGGL(k_gemm, dim3((N+BM-1)/BM, FDIM/BN), dim3(256), 0, stream,
                       h, W, A, z16, s_src, s_dst, N);
    hipLaunchKernelGGL(k_count, dim3((E+255)/256), dim3(256), 0, stream,
                       dst, counts, E);
    hipLaunchKernelGGL(k_chunk_sums, dim3(nb), dim3(256), 0, stream,
                       counts, bsums, N);
    hipLaunchKernelGGL(k_scan_small, dim3(1), dim3(1024), 0, stream,
                       bsums, nb);
    hipLaunchKernelGGL(k_scan_chunks, dim3(nb), dim3(256), 0, stream,
                       counts, cursor, bsums, N, E);
    hipLaunchKernelGGL(k_edge, dim3((E+15)/16), dim3(256), 0, stream,
                       ef, A, s_src, s_dst, src, dst, mbuf, cursor, epair, E);
    hipLaunchKernelGGL(k_out, dim3((N+3)/4), dim3(256), 0, stream,
                       z16, counts, epair, mbuf, out, N);
}

// Round 7
// 230.359 us; speedup vs baseline: 1.8237x; 1.0300x over previous
//
#include <hip/hip_runtime.h>
#include <hip/hip_bf16.h>

#define FDIM 256
#define EDIM 64
#define LEAKY 0.2f

// MFMA GEMM tiling
#define BM 128
#define BN 128
#define BK 32

typedef __attribute__((ext_vector_type(8))) short bfrag;   // 8 bf16 = 4 VGPR
typedef __attribute__((ext_vector_type(4))) float f4acc;   // 4 f32 accum

// fp32 -> bf16 bits, round-to-nearest-even
__device__ __forceinline__ unsigned f2bf(float x){
    unsigned u = __float_as_uint(x);
    return (u + 0x7FFFu + ((u >> 16) & 1u)) >> 16;
}
// exact float value of a bf16 bit pattern
__device__ __forceinline__ float bf2f(unsigned b){
    return __uint_as_float(b << 16);
}
__device__ __forceinline__ unsigned pack_hi(float x, float y, float& hx, float& hy){
    unsigned bx = f2bf(x), by = f2bf(y);
    hx = bf2f(bx); hy = bf2f(by);
    return bx | (by << 16);
}
__device__ __forceinline__ unsigned pack_lo(float rx, float ry){
    return f2bf(rx) | (f2bf(ry) << 16);
}

__global__ void k_init(float* __restrict__ s_src, float* __restrict__ s_dst,
                       int* __restrict__ counts, int N){
    int i = blockIdx.x*256 + threadIdx.x;
    if (i < N){ s_src[i] = 0.f; s_dst[i] = 0.f; counts[i] = 0; }
}

// z = h @ W^T via split-bf16 MFMA: A = hi+lo, B = hi only.
// acc += Ah*Bh + Al*Bh  (~2^-9 relative err, within tol). Output bf16.
// Epilogue computes partial s_src/s_dst and atomicAdds.
__global__ __launch_bounds__(256, 2) void k_gemm(const float* __restrict__ h,
                                                 const float* __restrict__ W,
                                                 const float* __restrict__ A,
                                                 unsigned short* __restrict__ z16,
                                                 float* __restrict__ s_src,
                                                 float* __restrict__ s_dst, int M){
    __shared__ uint4 smA[BM*8];
    __shared__ uint4 smB[BN*8];
    __shared__ float sred[2][2][BM];   // [wn-half][src/dst][row]

    int tid = threadIdx.x;
    int m0 = blockIdx.x * BM;
    int n0 = blockIdx.y * BN;

    int wid  = tid >> 6;
    int lane = tid & 63;
    int wm = (wid >> 1) * 64;
    int wn = (wid & 1) * 64;
    int l15 = lane & 15;
    int l4  = lane >> 4;

    f4acc acc[4][4];
    #pragma unroll
    for (int i = 0; i < 4; ++i)
        #pragma unroll
        for (int j = 0; j < 4; ++j)
            acc[i][j] = (f4acc)(0.f);

    for (int kc = 0; kc < FDIM; kc += BK){
        #pragma unroll
        for (int q = 0; q < 4; ++q){
            int p = tid + q*256;          // 0..511 = A (hi+lo), 512..1023 = B (hi)
            int isB = p >= 512;
            int pp = p & 511;
            int row = pp >> 2, k8 = pp & 3;
            float4 v0, v1;
            if (isB){
                const float* g = &W[(n0 + row)*FDIM + kc + k8*8];
                v0 = *(const float4*)g; v1 = *(const float4*)(g + 4);
            } else {
                int gr = m0 + row;
                if (gr < M){
                    const float* g = &h[(size_t)gr*FDIM + kc + k8*8];
                    v0 = *(const float4*)g; v1 = *(const float4*)(g + 4);
                } else {
                    v0 = make_float4(0.f,0.f,0.f,0.f); v1 = v0;
                }
            }
            int sh = k8 ^ (row & 7);
            if (isB){
                uint4 hi; float hx, hy;
                hi.x = pack_hi(v0.x, v0.y, hx, hy);
                hi.y = pack_hi(v0.z, v0.w, hx, hy);
                hi.z = pack_hi(v1.x, v1.y, hx, hy);
                hi.w = pack_hi(v1.z, v1.w, hx, hy);
                smB[row*8 + sh] = hi;
            } else {
                uint4 hi, lo; float hx, hy;
                hi.x = pack_hi(v0.x, v0.y, hx, hy);
                lo.x = pack_lo(v0.x - hx, v0.y - hy);
                hi.y = pack_hi(v0.z, v0.w, hx, hy);
                lo.y = pack_lo(v0.z - hx, v0.w - hy);
                hi.z = pack_hi(v1.x, v1.y, hx, hy);
                lo.z = pack_lo(v1.x - hx, v1.y - hy);
                hi.w = pack_hi(v1.z, v1.w, hx, hy);
                lo.w = pack_lo(v1.z - hx, v1.w - hy);
                smA[row*8 + sh]       = hi;
                smA[row*8 + (sh ^ 4)] = lo;
            }
        }
        __syncthreads();

        bfrag ah[4], al[4];
        #pragma unroll
        for (int mf = 0; mf < 4; ++mf){
            int row = wm + mf*16 + l15;
            int sh = l4 ^ (row & 7);
            ah[mf] = *(const bfrag*)&smA[row*8 + sh];
            al[mf] = *(const bfrag*)&smA[row*8 + (sh ^ 4)];
        }
        #pragma unroll
        for (int nf = 0; nf < 4; ++nf){
            int row = wn + nf*16 + l15;
            int sh = l4 ^ (row & 7);
            bfrag bh = *(const bfrag*)&smB[row*8 + sh];
            #pragma unroll
            for (int mf = 0; mf < 4; ++mf){
                acc[mf][nf] = __builtin_amdgcn_mfma_f32_16x16x32_bf16(ah[mf], bh, acc[mf][nf], 0, 0, 0);
                acc[mf][nf] = __builtin_amdgcn_mfma_f32_16x16x32_bf16(al[mf], bh, acc[mf][nf], 0, 0, 0);
            }
        }
        __syncthreads();
    }

    // ---- z write (bf16) ----
    #pragma unroll
    for (int mf = 0; mf < 4; ++mf){
        #pragma unroll
        for (int nf = 0; nf < 4; ++nf){
            int gcol = n0 + wn + nf*16 + l15;
            #pragma unroll
            for (int r = 0; r < 4; ++r){
                int grow = m0 + wm + mf*16 + l4*4 + r;
                if (grow < M)
                    z16[(size_t)grow*FDIM + gcol] = (unsigned short)f2bf(acc[mf][nf][r]);
            }
        }
    }

    // ---- fused partial s_src / s_dst ----
    float aS[4], aD[4];
    #pragma unroll
    for (int nf = 0; nf < 4; ++nf){
        int gcol = n0 + wn + nf*16 + l15;
        aS[nf] = A[gcol];
        aD[nf] = A[FDIM + gcol];
    }
    #pragma unroll
    for (int mf = 0; mf < 4; ++mf){
        #pragma unroll
        for (int r = 0; r < 4; ++r){
            float ps = 0.f, pd = 0.f;
            #pragma unroll
            for (int nf = 0; nf < 4; ++nf){
                ps += acc[mf][nf][r] * aS[nf];
                pd += acc[mf][nf][r] * aD[nf];
            }
            #pragma unroll
            for (int o = 1; o < 16; o <<= 1){
                ps += __shfl_xor(ps, o);
                pd += __shfl_xor(pd, o);
            }
            if (l15 == 0){
                int row = wm + mf*16 + l4*4 + r;
                sred[wid & 1][0][row] = ps;
                sred[wid & 1][1][row] = pd;
            }
        }
    }
    __syncthreads();
    if (tid < BM){
        int grow = m0 + tid;
        if (grow < M){
            atomicAdd(&s_src[grow], sred[0][0][tid] + sred[1][0][tid]);
            atomicAdd(&s_dst[grow], sred[0][1][tid] + sred[1][1][tid]);
        }
    }
}

// degree histogram
__global__ void k_count(const int* __restrict__ dst, int* __restrict__ counts, int E){
    int e = blockIdx.x*256 + threadIdx.x;
    if (e < E) atomicAdd(&counts[dst[e]], 1);
}

// scan phase 1: per-1024-chunk sums
__global__ void k_chunk_sums(const int* __restrict__ counts, int* __restrict__ bsums, int N){
    __shared__ int sh[256];
    int base = blockIdx.x*1024;
    int s = 0;
    for (int i = threadIdx.x; i < 1024; i += 256){
        int idx = base + i;
        s += (idx < N) ? counts[idx] : 0;
    }
    sh[threadIdx.x] = s; __syncthreads();
    for (int o = 128; o > 0; o >>= 1){
        if (threadIdx.x < o) sh[threadIdx.x] += sh[threadIdx.x + o];
        __syncthreads();
    }
    if (threadIdx.x == 0) bsums[blockIdx.x] = sh[0];
}

// scan phase 2: exclusive scan of chunk sums (nb <= 1024), single block
__global__ void k_scan_small(int* __restrict__ b, int nb){
    __shared__ int sh[1024];
    int tid = threadIdx.x;
    int v = (tid < nb) ? b[tid] : 0;
    sh[tid] = v; __syncthreads();
    int acc = v;
    for (int o = 1; o < 1024; o <<= 1){
        int t = (tid >= o) ? sh[tid - o] : 0;
        __syncthreads();
        acc += t; sh[tid] = acc;
        __syncthreads();
    }
    if (tid < nb) b[tid] = acc - v;
}

// scan phase 3: per-chunk exclusive scan -> offsets (in place) + cursor copy
__global__ void k_scan_chunks(int* __restrict__ counts, int* __restrict__ cursor,
                              const int* __restrict__ bsums, int N, int E){
    __shared__ int sh[256];
    int tid = threadIdx.x;
    int base = blockIdx.x*1024 + tid*4;
    int v[4]; int s = 0;
    #pragma unroll
    for (int l = 0; l < 4; l++){
        int idx = base + l;
        v[l] = (idx < N) ? counts[idx] : 0;
        s += v[l];
    }
    sh[tid] = s; __syncthreads();
    int acc = s;
    for (int o = 1; o < 256; o <<= 1){
        int t = (tid >= o) ? sh[tid - o] : 0;
        __syncthreads();
        acc += t; sh[tid] = acc;
        __syncthreads();
    }
    int excl = acc - s + bsums[blockIdx.x];
    #pragma unroll
    for (int l = 0; l < 4; l++){
        int idx = base + l;
        if (idx < N){ counts[idx] = excl; cursor[idx] = excl; }
        excl += v[l];
    }
    if (blockIdx.x == 0 && tid == 0) counts[N] = E;
}

// per-edge: e_feat dot + logit + leaky-relu + counting-sort write {src, logit}
__global__ void k_edge(const float* __restrict__ ef, const float* __restrict__ A,
                       const float* __restrict__ s_src, const float* __restrict__ s_dst,
                       const int* __restrict__ src, const int* __restrict__ dst,
                       int* __restrict__ cursor, int2* __restrict__ epair, int E){
    int gt = blockIdx.x*256 + threadIdx.x;
    int e = gt >> 4, l4 = gt & 15;
    if (e >= E) return;
    float4 f  = *(const float4*)&ef[(size_t)e*EDIM + l4*4];
    float4 ae = *(const float4*)&A[2*FDIM + l4*4];
    float v = f.x*ae.x + f.y*ae.y + f.z*ae.z + f.w*ae.w;
    v += __shfl_xor(v, 8); v += __shfl_xor(v, 4);
    v += __shfl_xor(v, 2); v += __shfl_xor(v, 1);
    if (l4 == 0){
        int d = dst[e];
        float lg = v + s_src[src[e]] + s_dst[d];
        lg = lg > 0.f ? lg : LEAKY*lg;
        int p = atomicAdd(&cursor[d], 1);
        int2 pr; pr.x = src[e]; pr.y = __float_as_int(lg);
        epair[p] = pr;
    }
}

// final: 4 dst nodes per block, one wave per node. Coalesced epair load once
// per 64-edge chunk; per-edge {w, src} distributed via shfl (no broadcast VMEM).
// In-wave segment max + denom (no mbuf).
__global__ __launch_bounds__(256) void k_out(const unsigned short* __restrict__ z16,
                                             const int* __restrict__ offsets,
                                             const int2* __restrict__ epair,
                                             float* __restrict__ out, int N){
    int n = blockIdx.x*4 + (threadIdx.x >> 6);
    int lane = threadIdx.x & 63;
    if (n >= N) return;
    int i0 = offsets[n], i1 = offsets[n+1];

    // per-lane strided max, then wave-reduce
    float mlane = -3.402823466e38f;
    for (int i = i0 + lane; i < i1; i += 64)
        mlane = fmaxf(mlane, __int_as_float(epair[i].y));
    float mx = mlane;
    #pragma unroll
    for (int o = 32; o > 0; o >>= 1)
        mx = fmaxf(mx, __shfl_xor(mx, o));

    float4 a[4];
    a[0] = make_float4(0,0,0,0); a[1] = a[0]; a[2] = a[0]; a[3] = a[0];
    float dw = 0.f;
    const unsigned short* zb = z16 + lane*4;

    for (int base = i0; base < i1; base += 64){
        int cnt = min(64, i1 - base);
        int2 pe = make_int2(0, 0);
        float w = 0.f;
        if (lane < cnt){
            pe = epair[base + lane];
            w = __expf(__int_as_float(pe.y) - mx);
        }
        dw += w;
        int j = 0;
        for (; j + 7 < cnt; j += 8){
            float wj[8]; int sj[8]; uint2 rj[8];
            #pragma unroll
            for (int q = 0; q < 8; ++q){
                wj[q] = __shfl(w, j + q);
                sj[q] = __shfl(pe.x, j + q);
            }
            #pragma unroll
            for (int q = 0; q < 8; ++q)
                rj[q] = *(const uint2*)&zb[(size_t)sj[q]*FDIM];
            #pragma unroll
            for (int q = 0; q < 8; ++q){
                a[q & 3].x += wj[q]*bf2f(rj[q].x & 0xffffu);
                a[q & 3].y += wj[q]*bf2f(rj[q].x >> 16);
                a[q & 3].z += wj[q]*bf2f(rj[q].y & 0xffffu);
                a[q & 3].w += wj[q]*bf2f(rj[q].y >> 16);
            }
        }
        for (; j < cnt; ++j){
            float wq = __shfl(w, j);
            int   sq = __shfl(pe.x, j);
            uint2 r0 = *(const uint2*)&zb[(size_t)sq*FDIM];
            a[0].x += wq*bf2f(r0.x & 0xffffu);
            a[0].y += wq*bf2f(r0.x >> 16);
            a[0].z += wq*bf2f(r0.y & 0xffffu);
            a[0].w += wq*bf2f(r0.y >> 16);
        }
    }

    // wave-reduce denom
    #pragma unroll
    for (int o = 32; o > 0; o >>= 1)
        dw += __shfl_xor(dw, o);

    float inv = (i1 > i0) ? 1.f / dw : 0.f;
    float4 res;
    res.x = ((a[0].x + a[1].x) + (a[2].x + a[3].x)) * inv;
    res.y = ((a[0].y + a[1].y) + (a[2].y + a[3].y)) * inv;
    res.z = ((a[0].z + a[1].z) + (a[2].z + a[3].z)) * inv;
    res.w = ((a[0].w + a[1].w) + (a[2].w + a[3].w)) * inv;
    *(float4*)&out[(size_t)n*FDIM + lane*4] = res;
}

extern "C" void kernel_launch(void* const* d_in, const int* in_sizes, int n_in,
                              void* d_out, int out_size, void* d_ws, size_t ws_size,
                              hipStream_t stream){
    const float* h  = (const float*)d_in[0];
    const float* ef = (const float*)d_in[1];
    const float* W  = (const float*)d_in[2];
    const float* A  = (const float*)d_in[3];
    const int*  src = (const int*)d_in[4];
    const int*  dst = (const int*)d_in[5];
    float* out = (float*)d_out;
    int N = in_sizes[0] / FDIM;
    int E = in_sizes[4];

    char* ws = (char*)d_ws;
    size_t off = 0;
    auto alloc = [&](size_t nbytes)->char*{
        char* p = ws + off;
        off = (off + nbytes + 255) & ~(size_t)255;
        return p;
    };
    unsigned short* z16 = (unsigned short*)alloc((size_t)N*FDIM*2);
    float* s_src  = (float*)alloc((size_t)N*4);
    float* s_dst  = (float*)alloc((size_t)N*4);
    int*   counts = (int*)alloc((size_t)(N+1)*4);
    int*   cursor = (int*)alloc((size_t)N*4);
    int2*  epair  = (int2*)alloc((size_t)E*8);
    int*   bsums  = (int*)alloc(1024*4);

    int nb = (N + 1023)/1024;

    hipLaunchKernelGGL(k_init, dim3((N+255)/256), dim3(256), 0, stream,
                       s_src, s_dst, counts, N);
    hipLaunchKernelGGL(k_gemm, dim3((N+BM-1)/BM, FDIM/BN), dim3(256), 0, stream,
                       h, W, A, z16, s_src, s_dst, N);
    hipLaunchKernelGGL(k_count, dim3((E+255)/256), dim3(256), 0, stream,
                       dst, counts, E);
    hipLaunchKernelGGL(k_chunk_sums, dim3(nb), dim3(256), 0, stream,
                       counts, bsums, N);
    hipLaunchKernelGGL(k_scan_small, dim3(1), dim3(1024), 0, stream,
                       bsums, nb);
    hipLaunchKernelGGL(k_scan_chunks, dim3(nb), dim3(256), 0, stream,
                       counts, cursor, bsums, N, E);
    hipLaunchKernelGGL(k_edge, dim3((E+15)/16), dim3(256), 0, stream,
                       ef, A, s_src, s_dst, src, dst, cursor, epair, E);
    hipLaunchKernelGGL(k_out, dim3((N+3)/4), dim3(256), 0, stream,
                       z16, counts, epair, out, N);
}

// Round 8
// 230.162 us; speedup vs baseline: 1.8252x; 1.0009x over previous
//
#include <hip/hip_runtime.h>
#include <hip/hip_bf16.h>

#define FDIM 256
#define EDIM 64
#define LEAKY 0.2f

// MFMA GEMM tiling: full-width column block
#define BM 128
#define BN 256
#define BK 32

typedef __attribute__((ext_vector_type(8))) short bfrag;   // 8 bf16 = 4 VGPR
typedef __attribute__((ext_vector_type(4))) float f4acc;   // 4 f32 accum

// fp32 -> bf16 bits, round-to-nearest-even
__device__ __forceinline__ unsigned f2bf(float x){
    unsigned u = __float_as_uint(x);
    return (u + 0x7FFFu + ((u >> 16) & 1u)) >> 16;
}
__device__ __forceinline__ float bf2f(unsigned b){
    return __uint_as_float(b << 16);
}
__device__ __forceinline__ unsigned pack_hi(float x, float y, float& hx, float& hy){
    unsigned bx = f2bf(x), by = f2bf(y);
    hx = bf2f(bx); hy = bf2f(by);
    return bx | (by << 16);
}
__device__ __forceinline__ unsigned pack_lo(float rx, float ry){
    return f2bf(rx) | (f2bf(ry) << 16);
}

// W (fp32 256x256) -> bf16 once
__global__ void k_wconv(const float* __restrict__ W, unsigned short* __restrict__ W16){
    int i = (blockIdx.x*256 + threadIdx.x) * 4;   // 16384 threads x 4 elems
    float4 v = *(const float4*)&W[i];
    uint2 o;
    o.x = f2bf(v.x) | (f2bf(v.y) << 16);
    o.y = f2bf(v.z) | (f2bf(v.w) << 16);
    *(uint2*)&W16[i] = o;
}

// z = h @ W^T via split-bf16 MFMA: A = hi+lo (converted here), B = bf16 (pre-converted).
// acc += Ah*Bh + Al*Bh. Output bf16 z16 + complete s_src/s_dst per row (direct store).
__global__ __launch_bounds__(256, 2) void k_gemm(const float* __restrict__ h,
                                                 const unsigned short* __restrict__ W16,
                                                 const float* __restrict__ A,
                                                 unsigned short* __restrict__ z16,
                                                 float* __restrict__ s_src,
                                                 float* __restrict__ s_dst, int M){
    __shared__ uint4 smA[BM*8];       // 16 KB: hi at slot k8^(row&7), lo at ^4
    __shared__ uint4 smB[BN*8];       // 32 KB: hi at slot k8^(row&7)
    __shared__ float sred[2][2][BM];  // [wn-half][src/dst][row]

    int tid = threadIdx.x;
    int m0 = blockIdx.x * BM;

    int wid  = tid >> 6;
    int lane = tid & 63;
    int wm = (wid >> 1) * 64;     // 0 / 64
    int wn = (wid & 1) * 128;     // 0 / 128
    int l15 = lane & 15;
    int l4  = lane >> 4;

    f4acc acc[4][8];
    #pragma unroll
    for (int i = 0; i < 4; ++i)
        #pragma unroll
        for (int j = 0; j < 8; ++j)
            acc[i][j] = (f4acc)(0.f);

    for (int kc = 0; kc < FDIM; kc += BK){
        // stage: A = 512 items (hi+lo conversion), B = 1024 items (copy)
        #pragma unroll
        for (int q = 0; q < 6; ++q){
            int p = tid + q*256;
            if (p < 512){
                int row = p >> 2, k8 = p & 3;
                int gr = m0 + row;
                float4 v0, v1;
                if (gr < M){
                    const float* g = &h[(size_t)gr*FDIM + kc + k8*8];
                    v0 = *(const float4*)g; v1 = *(const float4*)(g + 4);
                } else {
                    v0 = make_float4(0.f,0.f,0.f,0.f); v1 = v0;
                }
                uint4 hi, lo; float hx, hy;
                hi.x = pack_hi(v0.x, v0.y, hx, hy);
                lo.x = pack_lo(v0.x - hx, v0.y - hy);
                hi.y = pack_hi(v0.z, v0.w, hx, hy);
                lo.y = pack_lo(v0.z - hx, v0.w - hy);
                hi.z = pack_hi(v1.x, v1.y, hx, hy);
                lo.z = pack_lo(v1.x - hx, v1.y - hy);
                hi.w = pack_hi(v1.z, v1.w, hx, hy);
                lo.w = pack_lo(v1.z - hx, v1.w - hy);
                int sh = k8 ^ (row & 7);
                smA[row*8 + sh]       = hi;
                smA[row*8 + (sh ^ 4)] = lo;
            } else {
                int pb = p - 512;
                int row = pb >> 2, k8 = pb & 3;   // row 0..255 = output col
                uint4 v = *(const uint4*)&W16[(size_t)row*FDIM + kc + k8*8];
                smB[row*8 + (k8 ^ (row & 7))] = v;
            }
        }
        __syncthreads();

        bfrag ah[4], al[4];
        #pragma unroll
        for (int mf = 0; mf < 4; ++mf){
            int row = wm + mf*16 + l15;
            int sh = l4 ^ (row & 7);
            ah[mf] = *(const bfrag*)&smA[row*8 + sh];
            al[mf] = *(const bfrag*)&smA[row*8 + (sh ^ 4)];
        }
        #pragma unroll
        for (int nf = 0; nf < 8; ++nf){
            int row = wn + nf*16 + l15;
            bfrag bh = *(const bfrag*)&smB[row*8 + (l4 ^ (row & 7))];
            #pragma unroll
            for (int mf = 0; mf < 4; ++mf){
                acc[mf][nf] = __builtin_amdgcn_mfma_f32_16x16x32_bf16(ah[mf], bh, acc[mf][nf], 0, 0, 0);
                acc[mf][nf] = __builtin_amdgcn_mfma_f32_16x16x32_bf16(al[mf], bh, acc[mf][nf], 0, 0, 0);
            }
        }
        __syncthreads();
    }

    // ---- z write (bf16): col = wn + nf*16 + l15, row = wm + mf*16 + l4*4 + r
    #pragma unroll
    for (int mf = 0; mf < 4; ++mf){
        #pragma unroll
        for (int nf = 0; nf < 8; ++nf){
            int gcol = wn + nf*16 + l15;
            #pragma unroll
            for (int r = 0; r < 4; ++r){
                int grow = m0 + wm + mf*16 + l4*4 + r;
                if (grow < M)
                    z16[(size_t)grow*FDIM + gcol] = (unsigned short)f2bf(acc[mf][nf][r]);
            }
        }
    }

    // ---- fused s_src / s_dst (complete per block, direct store) ----
    float aS[8], aD[8];
    #pragma unroll
    for (int nf = 0; nf < 8; ++nf){
        int gcol = wn + nf*16 + l15;
        aS[nf] = A[gcol];
        aD[nf] = A[FDIM + gcol];
    }
    #pragma unroll
    for (int mf = 0; mf < 4; ++mf){
        #pragma unroll
        for (int r = 0; r < 4; ++r){
            float ps = 0.f, pd = 0.f;
            #pragma unroll
            for (int nf = 0; nf < 8; ++nf){
                ps += acc[mf][nf][r] * aS[nf];
                pd += acc[mf][nf][r] * aD[nf];
            }
            #pragma unroll
            for (int o = 1; o < 16; o <<= 1){
                ps += __shfl_xor(ps, o);
                pd += __shfl_xor(pd, o);
            }
            if (l15 == 0){
                int row = wm + mf*16 + l4*4 + r;
                sred[wid & 1][0][row] = ps;
                sred[wid & 1][1][row] = pd;
            }
        }
    }
    __syncthreads();
    if (tid < BM){
        int grow = m0 + tid;
        if (grow < M){
            s_src[grow] = sred[0][0][tid] + sred[1][0][tid];
            s_dst[grow] = sred[0][1][tid] + sred[1][1][tid];
        }
    }
}

// degree histogram
__global__ void k_count(const int* __restrict__ dst, int* __restrict__ counts, int E){
    int e = blockIdx.x*256 + threadIdx.x;
    if (e < E) atomicAdd(&counts[dst[e]], 1);
}

// scan phase 1: per-1024-chunk sums
__global__ void k_chunk_sums(const int* __restrict__ counts, int* __restrict__ bsums, int N){
    __shared__ int sh[256];
    int base = blockIdx.x*1024;
    int s = 0;
    for (int i = threadIdx.x; i < 1024; i += 256){
        int idx = base + i;
        s += (idx < N) ? counts[idx] : 0;
    }
    sh[threadIdx.x] = s; __syncthreads();
    for (int o = 128; o > 0; o >>= 1){
        if (threadIdx.x < o) sh[threadIdx.x] += sh[threadIdx.x + o];
        __syncthreads();
    }
    if (threadIdx.x == 0) bsums[blockIdx.x] = sh[0];
}

// scan phase 2: exclusive scan of chunk sums (nb <= 1024), single block
__global__ void k_scan_small(int* __restrict__ b, int nb){
    __shared__ int sh[1024];
    int tid = threadIdx.x;
    int v = (tid < nb) ? b[tid] : 0;
    sh[tid] = v; __syncthreads();
    int acc = v;
    for (int o = 1; o < 1024; o <<= 1){
        int t = (tid >= o) ? sh[tid - o] : 0;
        __syncthreads();
        acc += t; sh[tid] = acc;
        __syncthreads();
    }
    if (tid < nb) b[tid] = acc - v;
}

// scan phase 3: per-chunk exclusive scan -> offsets (in place) + cursor copy
__global__ void k_scan_chunks(int* __restrict__ counts, int* __restrict__ cursor,
                              const int* __restrict__ bsums, int N, int E){
    __shared__ int sh[256];
    int tid = threadIdx.x;
    int base = blockIdx.x*1024 + tid*4;
    int v[4]; int s = 0;
    #pragma unroll
    for (int l = 0; l < 4; l++){
        int idx = base + l;
        v[l] = (idx < N) ? counts[idx] : 0;
        s += v[l];
    }
    sh[tid] = s; __syncthreads();
    int acc = s;
    for (int o = 1; o < 256; o <<= 1){
        int t = (tid >= o) ? sh[tid - o] : 0;
        __syncthreads();
        acc += t; sh[tid] = acc;
        __syncthreads();
    }
    int excl = acc - s + bsums[blockIdx.x];
    #pragma unroll
    for (int l = 0; l < 4; l++){
        int idx = base + l;
        if (idx < N){ counts[idx] = excl; cursor[idx] = excl; }
        excl += v[l];
    }
    if (blockIdx.x == 0 && tid == 0) counts[N] = E;
}

// per-edge: e_feat dot + logit + leaky-relu + counting-sort write {src, logit}
__global__ void k_edge(const float* __restrict__ ef, const float* __restrict__ A,
                       const float* __restrict__ s_src, const float* __restrict__ s_dst,
                       const int* __restrict__ src, const int* __restrict__ dst,
                       int* __restrict__ cursor, int2* __restrict__ epair, int E){
    int gt = blockIdx.x*256 + threadIdx.x;
    int e = gt >> 4, l4 = gt & 15;
    if (e >= E) return;
    float4 f  = *(const float4*)&ef[(size_t)e*EDIM + l4*4];
    float4 ae = *(const float4*)&A[2*FDIM + l4*4];
    float v = f.x*ae.x + f.y*ae.y + f.z*ae.z + f.w*ae.w;
    v += __shfl_xor(v, 8); v += __shfl_xor(v, 4);
    v += __shfl_xor(v, 2); v += __shfl_xor(v, 1);
    if (l4 == 0){
        int d = dst[e];
        float lg = v + s_src[src[e]] + s_dst[d];
        lg = lg > 0.f ? lg : LEAKY*lg;
        int p = atomicAdd(&cursor[d], 1);
        int2 pr; pr.x = src[e]; pr.y = __float_as_int(lg);
        epair[p] = pr;
    }
}

// final: 4 dst nodes per block, one wave per node; coalesced epair + shfl
__global__ __launch_bounds__(256) void k_out(const unsigned short* __restrict__ z16,
                                             const int* __restrict__ offsets,
                                             const int2* __restrict__ epair,
                                             float* __restrict__ out, int N){
    int n = blockIdx.x*4 + (threadIdx.x >> 6);
    int lane = threadIdx.x & 63;
    if (n >= N) return;
    int i0 = offsets[n], i1 = offsets[n+1];

    float mlane = -3.402823466e38f;
    for (int i = i0 + lane; i < i1; i += 64)
        mlane = fmaxf(mlane, __int_as_float(epair[i].y));
    float mx = mlane;
    #pragma unroll
    for (int o = 32; o > 0; o >>= 1)
        mx = fmaxf(mx, __shfl_xor(mx, o));

    float4 a[4];
    a[0] = make_float4(0,0,0,0); a[1] = a[0]; a[2] = a[0]; a[3] = a[0];
    float dw = 0.f;
    const unsigned short* zb = z16 + lane*4;

    for (int base = i0; base < i1; base += 64){
        int cnt = min(64, i1 - base);
        int2 pe = make_int2(0, 0);
        float w = 0.f;
        if (lane < cnt){
            pe = epair[base + lane];
            w = __expf(__int_as_float(pe.y) - mx);
        }
        dw += w;
        int j = 0;
        for (; j + 7 < cnt; j += 8){
            float wj[8]; int sj[8]; uint2 rj[8];
            #pragma unroll
            for (int q = 0; q < 8; ++q){
                wj[q] = __shfl(w, j + q);
                sj[q] = __shfl(pe.x, j + q);
            }
            #pragma unroll
            for (int q = 0; q < 8; ++q)
                rj[q] = *(const uint2*)&zb[(size_t)sj[q]*FDIM];
            #pragma unroll
            for (int q = 0; q < 8; ++q){
                a[q & 3].x += wj[q]*bf2f(rj[q].x & 0xffffu);
                a[q & 3].y += wj[q]*bf2f(rj[q].x >> 16);
                a[q & 3].z += wj[q]*bf2f(rj[q].y & 0xffffu);
                a[q & 3].w += wj[q]*bf2f(rj[q].y >> 16);
            }
        }
        for (; j < cnt; ++j){
            float wq = __shfl(w, j);
            int   sq = __shfl(pe.x, j);
            uint2 r0 = *(const uint2*)&zb[(size_t)sq*FDIM];
            a[0].x += wq*bf2f(r0.x & 0xffffu);
            a[0].y += wq*bf2f(r0.x >> 16);
            a[0].z += wq*bf2f(r0.y & 0xffffu);
            a[0].w += wq*bf2f(r0.y >> 16);
        }
    }

    #pragma unroll
    for (int o = 32; o > 0; o >>= 1)
        dw += __shfl_xor(dw, o);

    float inv = (i1 > i0) ? 1.f / dw : 0.f;
    float4 res;
    res.x = ((a[0].x + a[1].x) + (a[2].x + a[3].x)) * inv;
    res.y = ((a[0].y + a[1].y) + (a[2].y + a[3].y)) * inv;
    res.z = ((a[0].z + a[1].z) + (a[2].z + a[3].z)) * inv;
    res.w = ((a[0].w + a[1].w) + (a[2].w + a[3].w)) * inv;
    *(float4*)&out[(size_t)n*FDIM + lane*4] = res;
}

extern "C" void kernel_launch(void* const* d_in, const int* in_sizes, int n_in,
                              void* d_out, int out_size, void* d_ws, size_t ws_size,
                              hipStream_t stream){
    const float* h  = (const float*)d_in[0];
    const float* ef = (const float*)d_in[1];
    const float* W  = (const float*)d_in[2];
    const float* A  = (const float*)d_in[3];
    const int*  src = (const int*)d_in[4];
    const int*  dst = (const int*)d_in[5];
    float* out = (float*)d_out;
    int N = in_sizes[0] / FDIM;
    int E = in_sizes[4];

    char* ws = (char*)d_ws;
    size_t off = 0;
    auto alloc = [&](size_t nbytes)->char*{
        char* p = ws + off;
        off = (off + nbytes + 255) & ~(size_t)255;
        return p;
    };
    unsigned short* z16 = (unsigned short*)alloc((size_t)N*FDIM*2);
    unsigned short* W16 = (unsigned short*)alloc((size_t)FDIM*FDIM*2);
    float* s_src  = (float*)alloc((size_t)N*4);
    float* s_dst  = (float*)alloc((size_t)N*4);
    int*   counts = (int*)alloc((size_t)(N+1)*4);
    int*   cursor = (int*)alloc((size_t)N*4);
    int2*  epair  = (int2*)alloc((size_t)E*8);
    int*   bsums  = (int*)alloc(1024*4);

    int nb = (N + 1023)/1024;

    hipMemsetAsync(counts, 0, (size_t)(N+1)*4, stream);
    hipLaunchKernelGGL(k_wconv, dim3(64), dim3(256), 0, stream, W, W16);
    hipLaunchKernelGGL(k_gemm, dim3((N+BM-1)/BM), dim3(256), 0, stream,
                       h, W16, A, z16, s_src, s_dst, N);
    hipLaunchKernelGGL(k_count, dim3((E+255)/256), dim3(256), 0, stream,
                       dst, counts, E);
    hipLaunchKernelGGL(k_chunk_sums, dim3(nb), dim3(256), 0, stream,
                       counts, bsums, N);
    hipLaunchKernelGGL(k_scan_small, dim3(1), dim3(1024), 0, stream,
                       bsums, nb);
    hipLaunchKernelGGL(k_scan_chunks, dim3(nb), dim3(256), 0, stream,
                       counts, cursor, bsums, N, E);
    hipLaunchKernelGGL(k_edge, dim3((E+15)/16), dim3(256), 0, stream,
                       ef, A, s_src, s_dst, src, dst, cursor, epair, E);
    hipLaunchKernelGGL(k_out, dim3((N+3)/4), dim3(256), 0, stream,
                       z16, counts, epair, out, N);
}